// Round 7
// baseline (2724.497 us; speedup 1.0000x reference)
//
#include <hip/hip_runtime.h>
#include <hip/hip_bf16.h>
#include <cstdint>

typedef short short8 __attribute__((ext_vector_type(8)));
typedef float f32x4 __attribute__((ext_vector_type(4)));
typedef uint32_t u32x2 __attribute__((ext_vector_type(2)));
typedef unsigned short u16;

#define DEVINL __device__ __forceinline__

DEVINL u16 f32_to_bf16(float f) {
  uint32_t u = __builtin_bit_cast(uint32_t, f);
  u += 0x7FFFu + ((u >> 16) & 1u);   // RTNE; inputs are finite
  return (u16)(u >> 16);
}
DEVINL float bf16_to_f32(u16 b) {
  return __builtin_bit_cast(float, ((uint32_t)b) << 16);
}
DEVINL f32x4 mfma16(short8 a, short8 b, f32x4 c) {
  return __builtin_amdgcn_mfma_f32_16x16x32_bf16(a, b, c, 0, 0, 0);
}
// tanh(x) = 1 - 2/(1+e^{2x}); e^{2x} = exp2(x * 2*log2(e)). Inf-safe at both ends.
DEVINL float tanh_e2(float x) {
  float e = __builtin_amdgcn_exp2f(x * 2.88539008177793f);
  return 1.f - __fdividef(2.f, 1.f + e);
}
// packed f32x2 -> bf16x2 (RTNE)
DEVINL uint32_t cvt_pk_bf16(float lo, float hi) {
  uint32_t r;
  asm("v_cvt_pk_bf16_f32 %0, %1, %2" : "=v"(r) : "v"(lo), "v"(hi));
  return r;
}

// ---------------- fp32 -> bf16 convert ----------------
__global__ void conv_bf16(const float* __restrict__ src, u16* __restrict__ dst, long n) {
  long i = ((long)blockIdx.x * blockDim.x + threadIdx.x) * 4;
  long stride = (long)gridDim.x * blockDim.x * 4;
  for (; i < n; i += stride) {
    float4 v = *(const float4*)(src + i);
    uint64_t p = (uint64_t)f32_to_bf16(v.x)
               | ((uint64_t)f32_to_bf16(v.y) << 16)
               | ((uint64_t)f32_to_bf16(v.z) << 32)
               | ((uint64_t)f32_to_bf16(v.w) << 48);
    *(uint64_t*)(dst + i) = p;
  }
}

__global__ void prep_bias(const float* __restrict__ bih, const float* __restrict__ bhh,
                          float* __restrict__ b1, float* __restrict__ b2) {
  int i = threadIdx.x;   // 512 threads
  b1[i] = bih[i]       + bhh[i];
  b2[i] = bih[512 + i] + bhh[512 + i];
}

// ---------------- GEMM: C[M,N] = A[M,K] @ B[N,K]^T + bias ----------------
// MODE 0: float out, [M][N] (FC head).
// MODE 1: bf16 out scattered into rec's U fragment layout (16-block consumer):
//   (b,t,j): bx=b>>3, m=b&7, tid = (j>>6)*64 + ((j>>2)&3)*16 + m
//   u16 idx = ((t*16 + bx)*512 + tid)*16 + ((j>>4)&3)*4 + (j&3)
template <int MODE>
__launch_bounds__(512, 2)
__global__ void gemm_bt(const u16* __restrict__ A, const u16* __restrict__ B,
                        const float* __restrict__ bias, void* __restrict__ out,
                        int M, int N, int K) {
  __shared__ u16 lA[128 * 64];
  __shared__ u16 lB[128 * 64];
  const int tid  = threadIdx.x;
  const int lane = tid & 63;
  const int wave = tid >> 6;
  const int wr = wave >> 2;
  const int wc = wave & 3;
  const int q   = lane >> 4;
  const int r16 = lane & 15;
  const int brow = blockIdx.x * 128;
  const int bcol = blockIdx.y * 128;

  f32x4 acc[4][2];
#pragma unroll
  for (int i = 0; i < 4; ++i)
#pragma unroll
    for (int j = 0; j < 2; ++j) acc[i][j] = (f32x4){0.f, 0.f, 0.f, 0.f};

  const int nkt = K >> 6;
  for (int kt = 0; kt < nkt; ++kt) {
#pragma unroll
    for (int s = 0; s < 2; ++s) {
      int c   = tid * 2 + s;
      int row = c >> 3;
      int cb  = (c & 7) * 16;
      int dsw = cb ^ ((row & 7) << 4);
      short8 va = *(const short8*)(A + (size_t)(brow + row) * K + kt * 64 + (cb >> 1));
      *(short8*)((char*)lA + row * 128 + dsw) = va;
      short8 vb = *(const short8*)(B + (size_t)(bcol + row) * K + kt * 64 + (cb >> 1));
      *(short8*)((char*)lB + row * 128 + dsw) = vb;
    }
    __syncthreads();
#pragma unroll
    for (int kk = 0; kk < 2; ++kk) {
      short8 af[4], bfr[2];
#pragma unroll
      for (int mt = 0; mt < 4; ++mt) {
        int row = wr * 64 + mt * 16 + r16;
        int byt = (kk * 64 + q * 16) ^ ((row & 7) << 4);
        af[mt] = *(const short8*)((const char*)lA + row * 128 + byt);
      }
#pragma unroll
      for (int nt = 0; nt < 2; ++nt) {
        int row = wc * 32 + nt * 16 + r16;
        int byt = (kk * 64 + q * 16) ^ ((row & 7) << 4);
        bfr[nt] = *(const short8*)((const char*)lB + row * 128 + byt);
      }
#pragma unroll
      for (int mt = 0; mt < 4; ++mt)
#pragma unroll
        for (int nt = 0; nt < 2; ++nt)
          acc[mt][nt] = mfma16(af[mt], bfr[nt], acc[mt][nt]);
    }
    __syncthreads();
  }

#pragma unroll
  for (int mt = 0; mt < 4; ++mt) {
#pragma unroll
    for (int nt = 0; nt < 2; ++nt) {
      int jc = bcol + wc * 32 + nt * 16 + r16;
      float bv = bias[jc];
      if (MODE == 0) {
#pragma unroll
        for (int rg = 0; rg < 4; ++rg) {
          int mg = brow + wr * 64 + mt * 16 + q * 4 + rg;
          ((float*)out)[(size_t)mg * N + jc] = acc[mt][nt][rg] + bv;
        }
      } else {
        int tidc    = (jc >> 6) * 64 + ((jc >> 2) & 3) * 16;   // + m
        int colpart = ((jc >> 4) & 3) * 4 + (jc & 3);
#pragma unroll
        for (int rg = 0; rg < 4; ++rg) {
          int mg = brow + wr * 64 + mt * 16 + q * 4 + rg;
          int bb = mg >> 9;        // batch index (T=512)
          int t2 = mg & 511;       // time index
          size_t idx = (((size_t)t2 * 16 + (bb >> 3)) * 512 + tidc + (bb & 7)) * 16 + colpart;
          ((u16*)out)[idx] = f32_to_bf16(acc[mt][nt][rg] + bv);
        }
      }
    }
  }
}

// ---------------- Recurrence: h_t = tanh(U_t + h_{t-1} @ Whh^T) ----------------
// 16 blocks x 8 batch rows (batch 125 -> 16x8, rows 125..127 pad). 8 waves,
// 2 waves/SIMD. Wave w owns j-cols [w*64, w*64+64): tiles 0..2 in regs (192),
// tile 3 in LDS (128 KiB total). h dbuf = 2 x 8 KiB ([kk][q][m8][16B]).
// Lanes r16>=8 are MFMA-dead (duplicate h reads broadcast for free; stores
// exec-masked off). Per-CU LDS/step: 192 KB < MFMA 2483 cyc -> matrix-bound.
__attribute__((amdgpu_flat_work_group_size(512, 512), amdgpu_waves_per_eu(2, 2)))
__global__ void rnn_rec(const u16* __restrict__ Whh,
                        const u16* __restrict__ Ufrag,  // [512 t][16 bx][512 tid][16]
                        u16* __restrict__ Hout,         // [128][512][512] bf16
                        float* __restrict__ hidden) {   // [125][512] fp32
  __shared__ char LDS[147456];
  // [0,131072): W LDS tiles, wave w at w*16384, addr = kk*1024 + q*256 + r16*16
  // [131072,139264): h buf0   [139264,147456): h buf1, layout [kk][q][m8][16B]
  const int tid  = threadIdx.x;
  const int lane = tid & 63;
  const int w    = tid >> 6;          // 0..7
  const int q    = lane >> 4;
  const int r16  = lane & 15;
  const int m8   = r16 & 7;
  const bool valid = r16 < 8;
  const int bx   = blockIdx.x;

  // ---- W register tiles 0..2 (j = w*64 + tt*16 + r16) ----
  short8 wreg[3][16];
#pragma unroll
  for (int tt = 0; tt < 3; ++tt)
#pragma unroll
    for (int kk = 0; kk < 16; ++kk) {
      wreg[tt][kk] = *(const short8*)(Whh + (size_t)(w * 64 + tt * 16 + r16) * 512 + kk * 32 + q * 8);
      asm volatile("" : "+a"(wreg[tt][kk]));   // keep in AGPRs
    }

  // ---- W LDS tile 3 (j = w*64 + 48 + r16) ----
#pragma unroll
  for (int kk = 0; kk < 16; ++kk) {
    short8 v = *(const short8*)(Whh + (size_t)(w * 64 + 48 + r16) * 512 + kk * 32 + q * 8);
    *(short8*)(LDS + w * 16384 + kk * 1024 + q * 256 + r16 * 16) = v;
  }

  // ---- zero h buf0 (8 KiB) ----
  {
    short8 z = {0, 0, 0, 0, 0, 0, 0, 0};
    *(short8*)(LDS + 131072 + tid * 16) = z;
  }

  // ---- loop-invariant bases ----
  uint32_t rd  = 131072 + q * 128 + m8 * 16;                               // h read (buf0)
  uint32_t wrb = 139264 + (q >> 1) * 128 + r16 * 16 + (q & 1) * 8;         // h write (buf1), valid lanes
  const uint32_t wlb = w * 16384 + q * 256 + r16 * 16;                     // W LDS base
  const int jb = w * 64 + q * 4;
  const int b  = bx * 8 + r16;                                             // real row iff valid
  const char* Ub = (const char*)Ufrag;
  const uint32_t ubase = (uint32_t)(bx * 512 + w * 64 + q * 16 + m8) * 32; // invalid lanes alias valid
  char* Hc = (char*)Hout;
  uint32_t hoff = (uint32_t)(valid ? b : 125) * 524288u + (uint32_t)jb * 2u;

  // ---- prologue: load U[0], D-init, issue U[1], barrier ----
  short8 u  = *(const short8*)(Ub + ubase);
  short8 u2 = *(const short8*)(Ub + ubase + 16);
  f32x4 D0, D1, D2, D3;
#pragma unroll
  for (int rg = 0; rg < 4; ++rg) {
    D0[rg] = bf16_to_f32((u16)u[rg]);
    D1[rg] = bf16_to_f32((u16)u[rg + 4]);
    D2[rg] = bf16_to_f32((u16)u2[rg]);
    D3[rg] = bf16_to_f32((u16)u2[rg + 4]);
  }
  u  = *(const short8*)(Ub + ubase + 262144u);
  u2 = *(const short8*)(Ub + ubase + 262144u + 16);
  __syncthreads();

  for (int t = 0; t < 512; ++t) {
    // merged kk loop: hf (8KB dbuf, broadcast pairs) + wl (W tile), 4 MFMAs
#pragma unroll
    for (int kk = 0; kk < 16; ++kk) {
      short8 hf = *(const short8*)(LDS + rd + kk * 512);
      short8 wl = *(const short8*)(LDS + wlb + kk * 1024);
      D0 = mfma16(wreg[0][kk], hf, D0);
      D1 = mfma16(wreg[1][kk], hf, D1);
      D2 = mfma16(wreg[2][kk], hf, D2);
      D3 = mfma16(wl, hf, D3);
    }

    // epilogue: tanh -> pack -> LDS h(next) + global H (valid lanes only)
#define EPI_TILE(Dt, tt) { \
    float e0 = tanh_e2(Dt[0]), e1 = tanh_e2(Dt[1]); \
    float e2 = tanh_e2(Dt[2]), e3 = tanh_e2(Dt[3]); \
    u32x2 pk; pk[0] = cvt_pk_bf16(e0, e1); pk[1] = cvt_pk_bf16(e2, e3); \
    if (valid) { \
      *(u32x2*)(LDS + wrb + w * 1024 + (tt) * 256) = pk; \
      *(u32x2*)(Hc + hoff + (tt) * 32) = pk; \
    } \
  }
    EPI_TILE(D0, 0); EPI_TILE(D1, 1); EPI_TILE(D2, 2); EPI_TILE(D3, 3);
#undef EPI_TILE
    hoff += 1024;

    // D-init(t+1) from prefetched u; reuse u as t+2 prefetch buffer
    if (t < 511) {
#pragma unroll
      for (int rg = 0; rg < 4; ++rg) {
        D0[rg] = bf16_to_f32((u16)u[rg]);
        D1[rg] = bf16_to_f32((u16)u[rg + 4]);
        D2[rg] = bf16_to_f32((u16)u2[rg]);
        D3[rg] = bf16_to_f32((u16)u2[rg + 4]);
      }
      uint32_t off = ubase + (uint32_t)((t + 2 <= 511) ? (t + 2) : 511) * 262144u;
      u  = *(const short8*)(Ub + off);
      u2 = *(const short8*)(Ub + off + 16);
    }

    rd ^= 8192; wrb ^= 8192;   // swap h buffers
    asm volatile("s_waitcnt lgkmcnt(0)" ::: "memory");
    __builtin_amdgcn_s_barrier();
    asm volatile("" ::: "memory");
  }

  // ---- final hidden state: h(T-1) sits in buf0; read back own slots ----
  if (valid && b < 125) {
    uint32_t fwr = 131072 + (q >> 1) * 128 + r16 * 16 + (q & 1) * 8 + w * 1024;
#pragma unroll
    for (int tt = 0; tt < 4; ++tt) {
      u32x2 pk = *(const u32x2*)(LDS + fwr + tt * 256);
      float4 v;
      v.x = __builtin_bit_cast(float, pk[0] << 16);
      v.y = __builtin_bit_cast(float, pk[0] & 0xFFFF0000u);
      v.z = __builtin_bit_cast(float, pk[1] << 16);
      v.w = __builtin_bit_cast(float, pk[1] & 0xFFFF0000u);
      *(float4*)(hidden + (size_t)b * 512 + jb + tt * 16) = v;
    }
  }
}

extern "C" void kernel_launch(void* const* d_in, const int* in_sizes, int n_in,
                              void* d_out, int out_size, void* d_ws, size_t ws_size,
                              hipStream_t stream) {
  const float* x   = (const float*)d_in[0];
  const float* wih = (const float*)d_in[1];   // [2,512,512]
  const float* whh = (const float*)d_in[2];   // [2,512,512]
  const float* bih = (const float*)d_in[3];   // [2,512]
  const float* bhh = (const float*)d_in[4];   // [2,512]
  const float* fcw = (const float*)d_in[5];   // [1024,512]
  const float* fcb = (const float*)d_in[6];   // [1024]

  // workspace layout
  char* ws = (char*)d_ws;
  u16* Xb    = (u16*)ws;                          // 65,536,000 B
  u16* Hb    = (u16*)(ws + 65536000);             // 67,108,864 B ([128][512][512])
  u16* Wih1  = (u16*)(ws + 132644864);            // 524,288 B each
  u16* Whh1  = Wih1 + 262144;
  u16* Wih2  = Whh1 + 262144;
  u16* Whh2  = Wih2 + 262144;
  u16* FCW   = Whh2 + 262144;                     // 1 MB
  float* b1  = (float*)(FCW + 524288);
  float* b2  = b1 + 512;

  // U scratch (fragment layout, 134 MB) lives in d_out; dead before FC writes
  u16*   Ubf  = (u16*)d_out;
  float* outp = (float*)d_out;
  float* hid  = outp + 65536000;                  // [2][125][512]

  conv_bf16<<<2048, 256, 0, stream>>>(x, Xb, 32768000L);
  conv_bf16<<<256, 256, 0, stream>>>(wih,          Wih1, 262144L);
  conv_bf16<<<256, 256, 0, stream>>>(wih + 262144, Wih2, 262144L);
  conv_bf16<<<256, 256, 0, stream>>>(whh,          Whh1, 262144L);
  conv_bf16<<<256, 256, 0, stream>>>(whh + 262144, Whh2, 262144L);
  conv_bf16<<<512, 256, 0, stream>>>(fcw, FCW, 524288L);
  prep_bias<<<1, 512, 0, stream>>>(bih, bhh, b1, b2);

  dim3 blk(512);
  dim3 g1(500, 4);   // 64000/128 x 512/128
  dim3 g2(500, 8);   // 64000/128 x 1024/128

  // layer 1
  gemm_bt<1><<<g1, blk, 0, stream>>>(Xb, Wih1, b1, Ubf, 64000, 512, 512);
  rnn_rec<<<16, 512, 0, stream>>>(Whh1, Ubf, Hb, hid);
  // layer 2
  gemm_bt<1><<<g1, blk, 0, stream>>>(Hb, Wih2, b2, Ubf, 64000, 512, 512);
  rnn_rec<<<16, 512, 0, stream>>>(Whh2, Ubf, Hb, hid + 64000);
  // FC head
  gemm_bt<0><<<g2, blk, 0, stream>>>(Hb, FCW, fcb, d_out, 64000, 1024, 512);

  (void)in_sizes; (void)n_in; (void)out_size; (void)ws_size;
}

// Round 9
// 2612.365 us; speedup vs baseline: 1.0429x; 1.0429x over previous
//
#include <hip/hip_runtime.h>
#include <hip/hip_bf16.h>
#include <cstdint>

typedef short short8 __attribute__((ext_vector_type(8)));
typedef float f32x4 __attribute__((ext_vector_type(4)));
typedef uint32_t u32x2 __attribute__((ext_vector_type(2)));
typedef unsigned short u16;

#define DEVINL __device__ __forceinline__

DEVINL u16 f32_to_bf16(float f) {
  uint32_t u = __builtin_bit_cast(uint32_t, f);
  u += 0x7FFFu + ((u >> 16) & 1u);   // RTNE; inputs are finite
  return (u16)(u >> 16);
}
DEVINL float bf16_to_f32(u16 b) {
  return __builtin_bit_cast(float, ((uint32_t)b) << 16);
}
DEVINL f32x4 mfma16(short8 a, short8 b, f32x4 c) {
  return __builtin_amdgcn_mfma_f32_16x16x32_bf16(a, b, c, 0, 0, 0);
}
// tanh(x) = 1 - 2/(1+e^{2x}); e^{2x} = exp2(x * 2*log2(e)). Inf-safe at both ends.
DEVINL float tanh_e2(float x) {
  float e = __builtin_amdgcn_exp2f(x * 2.88539008177793f);
  return 1.f - __fdividef(2.f, 1.f + e);
}
// packed f32x2 -> bf16x2 (RTNE)
DEVINL uint32_t cvt_pk_bf16(float lo, float hi) {
  uint32_t r;
  asm("v_cvt_pk_bf16_f32 %0, %1, %2" : "=v"(r) : "v"(lo), "v"(hi));
  return r;
}

// ---------------- fp32 -> bf16 convert ----------------
__global__ void conv_bf16(const float* __restrict__ src, u16* __restrict__ dst, long n) {
  long i = ((long)blockIdx.x * blockDim.x + threadIdx.x) * 4;
  long stride = (long)gridDim.x * blockDim.x * 4;
  for (; i < n; i += stride) {
    float4 v = *(const float4*)(src + i);
    uint64_t p = (uint64_t)f32_to_bf16(v.x)
               | ((uint64_t)f32_to_bf16(v.y) << 16)
               | ((uint64_t)f32_to_bf16(v.z) << 32)
               | ((uint64_t)f32_to_bf16(v.w) << 48);
    *(uint64_t*)(dst + i) = p;
  }
}

__global__ void prep_bias(const float* __restrict__ bih, const float* __restrict__ bhh,
                          float* __restrict__ b1, float* __restrict__ b2) {
  int i = threadIdx.x;   // 512 threads
  b1[i] = bih[i]       + bhh[i];
  b2[i] = bih[512 + i] + bhh[512 + i];
}

// ---------------- GEMM: C[M,N] = A[M,K] @ B[N,K]^T + bias ----------------
// MODE 0: float out, [M][N] (FC head).
// MODE 1: FLOAT out scattered into rec's U fragment layout (8-block consumer):
//   (b,t,j): tid = (j>>6)*64 + ((j>>2)&3)*16 + (b&15)
//   f32 idx = ((t*8 + (b>>4))*512 + tid)*16 + ((j>>4)&3)*4 + (j&3)
template <int MODE>
__launch_bounds__(512, 2)
__global__ void gemm_bt(const u16* __restrict__ A, const u16* __restrict__ B,
                        const float* __restrict__ bias, void* __restrict__ out,
                        int M, int N, int K) {
  __shared__ u16 lA[128 * 64];
  __shared__ u16 lB[128 * 64];
  const int tid  = threadIdx.x;
  const int lane = tid & 63;
  const int wave = tid >> 6;
  const int wr = wave >> 2;
  const int wc = wave & 3;
  const int q   = lane >> 4;
  const int r16 = lane & 15;
  const int brow = blockIdx.x * 128;
  const int bcol = blockIdx.y * 128;

  f32x4 acc[4][2];
#pragma unroll
  for (int i = 0; i < 4; ++i)
#pragma unroll
    for (int j = 0; j < 2; ++j) acc[i][j] = (f32x4){0.f, 0.f, 0.f, 0.f};

  const int nkt = K >> 6;
  for (int kt = 0; kt < nkt; ++kt) {
#pragma unroll
    for (int s = 0; s < 2; ++s) {
      int c   = tid * 2 + s;
      int row = c >> 3;
      int cb  = (c & 7) * 16;
      int dsw = cb ^ ((row & 7) << 4);
      short8 va = *(const short8*)(A + (size_t)(brow + row) * K + kt * 64 + (cb >> 1));
      *(short8*)((char*)lA + row * 128 + dsw) = va;
      short8 vb = *(const short8*)(B + (size_t)(bcol + row) * K + kt * 64 + (cb >> 1));
      *(short8*)((char*)lB + row * 128 + dsw) = vb;
    }
    __syncthreads();
#pragma unroll
    for (int kk = 0; kk < 2; ++kk) {
      short8 af[4], bfr[2];
#pragma unroll
      for (int mt = 0; mt < 4; ++mt) {
        int row = wr * 64 + mt * 16 + r16;
        int byt = (kk * 64 + q * 16) ^ ((row & 7) << 4);
        af[mt] = *(const short8*)((const char*)lA + row * 128 + byt);
      }
#pragma unroll
      for (int nt = 0; nt < 2; ++nt) {
        int row = wc * 32 + nt * 16 + r16;
        int byt = (kk * 64 + q * 16) ^ ((row & 7) << 4);
        bfr[nt] = *(const short8*)((const char*)lB + row * 128 + byt);
      }
#pragma unroll
      for (int mt = 0; mt < 4; ++mt)
#pragma unroll
        for (int nt = 0; nt < 2; ++nt)
          acc[mt][nt] = mfma16(af[mt], bfr[nt], acc[mt][nt]);
    }
    __syncthreads();
  }

#pragma unroll
  for (int mt = 0; mt < 4; ++mt) {
#pragma unroll
    for (int nt = 0; nt < 2; ++nt) {
      int jc = bcol + wc * 32 + nt * 16 + r16;
      float bv = bias[jc];
      if (MODE == 0) {
#pragma unroll
        for (int rg = 0; rg < 4; ++rg) {
          int mg = brow + wr * 64 + mt * 16 + q * 4 + rg;
          ((float*)out)[(size_t)mg * N + jc] = acc[mt][nt][rg] + bv;
        }
      } else {
        int tidc    = (jc >> 6) * 64 + ((jc >> 2) & 3) * 16;   // + (bb&15)
        int colpart = ((jc >> 4) & 3) * 4 + (jc & 3);
#pragma unroll
        for (int rg = 0; rg < 4; ++rg) {
          int mg = brow + wr * 64 + mt * 16 + q * 4 + rg;
          int bb = mg >> 9;        // batch index (T=512)
          int t2 = mg & 511;       // time index
          size_t idx = (((size_t)t2 * 8 + (bb >> 4)) * 512 + tidc + (bb & 15)) * 16 + colpart;
          ((float*)out)[idx] = acc[mt][nt][rg] + bv;
        }
      }
    }
  }
}

// ---------------- Recurrence: h_t = tanh(U_t + h_{t-1} @ Whh^T) ----------------
// 8 blocks (16 batch rows each), 8 waves, 2 waves/SIMD (256-reg budget).
// Wave w owns j-cols [w*64, w*64+64): tiles 0..2 in arch VGPRs (192, NO pin),
// tile 3 in LDS. D accumulators PINNED TO AGPRs (the legitimate AGPR customer)
// so the allocator leaves wreg in VGPRs -> no per-MFMA AGPR<->VGPR copies.
// U is f32 fragments: D-init = 4 raw dwordx4 loads, zero unpack VALU.
__attribute__((amdgpu_flat_work_group_size(512, 512), amdgpu_waves_per_eu(2, 2)))
__global__ void rnn_rec(const u16* __restrict__ Whh,
                        const float* __restrict__ Ufrag, // [512 t][8 g][512 tid][16 f32]
                        u16* __restrict__ Hout,          // [128][512][512] bf16 (125..127 dump)
                        float* __restrict__ hidden) {    // [125][512] fp32
  __shared__ char LDS[163840];
  // [0,131072): W LDS tiles, wave w at w*16384, addr = kk*1024 + q*256 + r16*16
  // [131072,147456): h buf0   [147456,163840): h buf1, layout [kk][q][m16][16B]
  const int tid  = threadIdx.x;
  const int lane = tid & 63;
  const int w    = tid >> 6;          // 0..7
  const int q    = lane >> 4;
  const int r16  = lane & 15;
  const int g    = blockIdx.x;

  // ---- W register tiles 0..2 (j = w*64 + tt*16 + r16), natural allocation ----
  short8 wreg[3][16];
#pragma unroll
  for (int tt = 0; tt < 3; ++tt)
#pragma unroll
    for (int kk = 0; kk < 16; ++kk)
      wreg[tt][kk] = *(const short8*)(Whh + (size_t)(w * 64 + tt * 16 + r16) * 512 + kk * 32 + q * 8);

  // ---- W LDS tile 3 (j = w*64 + 48 + r16) ----
#pragma unroll
  for (int kk = 0; kk < 16; ++kk) {
    short8 v = *(const short8*)(Whh + (size_t)(w * 64 + 48 + r16) * 512 + kk * 32 + q * 8);
    *(short8*)(LDS + w * 16384 + kk * 1024 + q * 256 + r16 * 16) = v;
  }

  // ---- zero h buf0 (16 KiB) ----
  {
    short8 z = {0, 0, 0, 0, 0, 0, 0, 0};
    *(short8*)(LDS + 131072 + tid * 32)      = z;
    *(short8*)(LDS + 131072 + tid * 32 + 16) = z;
  }

  // ---- loop-invariant bases ----
  uint32_t rd = 131072 + q * 256 + r16 * 16;                 // h read base (buf0)
  uint32_t wr = 147456 + w * 2048 + (q >> 1) * 256 + r16 * 16 + (q & 1) * 8;  // write (buf1)
  const uint32_t wlb = w * 16384 + q * 256 + r16 * 16;       // W LDS base
  const int jb = w * 64 + q * 4;
  const char* Ub = (const char*)Ufrag;
  const uint32_t ubase = (uint32_t)(g * 512 + tid) * 64;     // bytes (16 f32/thread)
  char* Hc = (char*)Hout;
  uint32_t hoff = (uint32_t)(g * 16 + r16) * 524288u + (uint32_t)jb * 2u;  // += 1024/step

  // ---- prologue: issue U[0] loads, barrier (covers LDS init) ----
  f32x4 u0 = *(const f32x4*)(Ub + ubase);
  f32x4 u1 = *(const f32x4*)(Ub + ubase + 16);
  f32x4 u2 = *(const f32x4*)(Ub + ubase + 32);
  f32x4 u3 = *(const f32x4*)(Ub + ubase + 48);
  __syncthreads();

  for (int t = 0; t < 512; ++t) {
    // D init = plain moves into AGPR-pinned accumulators
    f32x4 D0 = u0, D1 = u1, D2 = u2, D3 = u3;
    asm volatile("" : "+a"(D0), "+a"(D1), "+a"(D2), "+a"(D3));

    // prefetch next step's U (f32, 64 B/thread; lands during kk loop + barrier)
    {
      uint32_t off = ubase + (uint32_t)((t + 1 <= 511) ? (t + 1) : 511) * 262144u;
      u0 = *(const f32x4*)(Ub + off);
      u1 = *(const f32x4*)(Ub + off + 16);
      u2 = *(const f32x4*)(Ub + off + 32);
      u3 = *(const f32x4*)(Ub + off + 48);
    }

    // merged kk loop: 1 hf + 1 wl ds_read_b128, 4 MFMAs (W from VGPR, D in AGPR)
#pragma unroll
    for (int kk = 0; kk < 16; ++kk) {
      short8 hf = *(const short8*)(LDS + rd + kk * 1024);
      short8 wl = *(const short8*)(LDS + wlb + kk * 1024);
      D0 = mfma16(wreg[0][kk], hf, D0);
      D1 = mfma16(wreg[1][kk], hf, D1);
      D2 = mfma16(wreg[2][kk], hf, D2);
      D3 = mfma16(wl, hf, D3);
    }

    // epilogue: tanh -> pack -> LDS h(next) + global H
#define EPI_TILE(Dt, tt) { \
    float e0 = tanh_e2(Dt[0]), e1 = tanh_e2(Dt[1]); \
    float e2 = tanh_e2(Dt[2]), e3 = tanh_e2(Dt[3]); \
    u32x2 pk; pk[0] = cvt_pk_bf16(e0, e1); pk[1] = cvt_pk_bf16(e2, e3); \
    *(u32x2*)(LDS + wr + ((tt) >> 1) * 1024 + ((tt) & 1) * 512) = pk; \
    *(u32x2*)(Hc + hoff + (tt) * 32) = pk; \
  }
    EPI_TILE(D0, 0); EPI_TILE(D1, 1); EPI_TILE(D2, 2); EPI_TILE(D3, 3);
#undef EPI_TILE
    hoff += 1024;

    rd ^= 16384; wr ^= 16384;   // swap h buffers
    asm volatile("s_waitcnt lgkmcnt(0)" ::: "memory");
    __builtin_amdgcn_s_barrier();
    asm volatile("" ::: "memory");
  }

  // ---- final hidden state: h(T-1) is in buf0 (512 swaps); read own slots ----
  {
    int b = g * 16 + r16;
    if (b < 125) {
      uint32_t fwr = 131072 + w * 2048 + (q >> 1) * 256 + r16 * 16 + (q & 1) * 8;
#pragma unroll
      for (int tt = 0; tt < 4; ++tt) {
        u32x2 pk = *(const u32x2*)(LDS + fwr + (tt >> 1) * 1024 + (tt & 1) * 512);
        float4 v;
        v.x = __builtin_bit_cast(float, pk[0] << 16);
        v.y = __builtin_bit_cast(float, pk[0] & 0xFFFF0000u);
        v.z = __builtin_bit_cast(float, pk[1] << 16);
        v.w = __builtin_bit_cast(float, pk[1] & 0xFFFF0000u);
        *(float4*)(hidden + (size_t)b * 512 + jb + tt * 16) = v;
      }
    }
  }
}

extern "C" void kernel_launch(void* const* d_in, const int* in_sizes, int n_in,
                              void* d_out, int out_size, void* d_ws, size_t ws_size,
                              hipStream_t stream) {
  const float* x   = (const float*)d_in[0];
  const float* wih = (const float*)d_in[1];   // [2,512,512]
  const float* whh = (const float*)d_in[2];   // [2,512,512]
  const float* bih = (const float*)d_in[3];   // [2,512]
  const float* bhh = (const float*)d_in[4];   // [2,512]
  const float* fcw = (const float*)d_in[5];   // [1024,512]
  const float* fcb = (const float*)d_in[6];   // [1024]

  // workspace layout
  char* ws = (char*)d_ws;
  u16* Xb    = (u16*)ws;                          // 65,536,000 B
  u16* Hb    = (u16*)(ws + 65536000);             // 67,108,864 B ([128][512][512])
  u16* Wih1  = (u16*)(ws + 132644864);            // 524,288 B each
  u16* Whh1  = Wih1 + 262144;
  u16* Wih2  = Whh1 + 262144;
  u16* Whh2  = Wih2 + 262144;
  u16* FCW   = Whh2 + 262144;                     // 1 MB
  float* b1  = (float*)(FCW + 524288);
  float* b2  = b1 + 512;

  // U scratch (f32 fragment layout, 134 MB) lives in d_out; dead before FC writes
  float* Ubf  = (float*)d_out;
  float* outp = (float*)d_out;
  float* hid  = outp + 65536000;                  // [2][125][512]

  conv_bf16<<<2048, 256, 0, stream>>>(x, Xb, 32768000L);
  conv_bf16<<<256, 256, 0, stream>>>(wih,          Wih1, 262144L);
  conv_bf16<<<256, 256, 0, stream>>>(wih + 262144, Wih2, 262144L);
  conv_bf16<<<256, 256, 0, stream>>>(whh,          Whh1, 262144L);
  conv_bf16<<<256, 256, 0, stream>>>(whh + 262144, Whh2, 262144L);
  conv_bf16<<<512, 256, 0, stream>>>(fcw, FCW, 524288L);
  prep_bias<<<1, 512, 0, stream>>>(bih, bhh, b1, b2);

  dim3 blk(512);
  dim3 g1(500, 4);   // 64000/128 x 512/128
  dim3 g2(500, 8);   // 64000/128 x 1024/128

  // layer 1
  gemm_bt<1><<<g1, blk, 0, stream>>>(Xb, Wih1, b1, Ubf, 64000, 512, 512);
  rnn_rec<<<8, 512, 0, stream>>>(Whh1, Ubf, Hb, hid);
  // layer 2
  gemm_bt<1><<<g1, blk, 0, stream>>>(Hb, Wih2, b2, Ubf, 64000, 512, 512);
  rnn_rec<<<8, 512, 0, stream>>>(Whh2, Ubf, Hb, hid + 64000);
  // FC head
  gemm_bt<0><<<g2, blk, 0, stream>>>(Hb, FCW, fcb, d_out, 64000, 1024, 512);

  (void)in_sizes; (void)n_in; (void)out_size; (void)ws_size;
}

// Round 11
// 1904.070 us; speedup vs baseline: 1.4309x; 1.3720x over previous
//
#include <hip/hip_runtime.h>
#include <hip/hip_bf16.h>
#include <cstdint>

typedef short short8 __attribute__((ext_vector_type(8)));
typedef float f32x4 __attribute__((ext_vector_type(4)));
typedef uint32_t u32x2 __attribute__((ext_vector_type(2)));
typedef unsigned short u16;

#define DEVINL __device__ __forceinline__

DEVINL u16 f32_to_bf16(float f) {
  uint32_t u = __builtin_bit_cast(uint32_t, f);
  u += 0x7FFFu + ((u >> 16) & 1u);   // RTNE; inputs are finite
  return (u16)(u >> 16);
}
DEVINL float bf16_to_f32(u16 b) {
  return __builtin_bit_cast(float, ((uint32_t)b) << 16);
}
DEVINL f32x4 mfma16(short8 a, short8 b, f32x4 c) {
  return __builtin_amdgcn_mfma_f32_16x16x32_bf16(a, b, c, 0, 0, 0);
}
// tanh(x) = 1 - 2/(1+e^{2x}); e^{2x} = exp2(x * 2*log2(e)). Inf-safe at both ends.
DEVINL float tanh_e2(float x) {
  float e = __builtin_amdgcn_exp2f(x * 2.88539008177793f);
  return 1.f - __fdividef(2.f, 1.f + e);
}
// packed f32x2 -> bf16x2 (RTNE)
DEVINL uint32_t cvt_pk_bf16(float lo, float hi) {
  uint32_t r;
  asm("v_cvt_pk_bf16_f32 %0, %1, %2" : "=v"(r) : "v"(lo), "v"(hi));
  return r;
}

// ---------------- fp32 -> bf16 convert ----------------
__global__ void conv_bf16(const float* __restrict__ src, u16* __restrict__ dst, long n) {
  long i = ((long)blockIdx.x * blockDim.x + threadIdx.x) * 4;
  long stride = (long)gridDim.x * blockDim.x * 4;
  for (; i < n; i += stride) {
    float4 v = *(const float4*)(src + i);
    uint64_t p = (uint64_t)f32_to_bf16(v.x)
               | ((uint64_t)f32_to_bf16(v.y) << 16)
               | ((uint64_t)f32_to_bf16(v.z) << 32)
               | ((uint64_t)f32_to_bf16(v.w) << 48);
    *(uint64_t*)(dst + i) = p;
  }
}

__global__ void prep_bias(const float* __restrict__ bih, const float* __restrict__ bhh,
                          float* __restrict__ b1, float* __restrict__ b2) {
  int i = threadIdx.x;   // 512 threads
  b1[i] = bih[i]       + bhh[i];
  b2[i] = bih[512 + i] + bhh[512 + i];
}

// ---------------- one 128-step recurrence window (r6-verified body) ----------------
// 8 waves, wave w owns j-cols [w*64,w*64+64): tiles 0..2 in regs, tile 3 in LDS.
// h state carried across windows via 16KB/block global image of LDS buf0.
DEVINL void rec_window(char* LDS, int g, const u16* __restrict__ Whh,
                       const u16* __restrict__ U, u16* __restrict__ Hout,
                       float* __restrict__ hidden, u16* __restrict__ hstate, int win) {
  const int tid  = threadIdx.x;
  const int lane = tid & 63;
  const int w    = tid >> 6;
  const int q    = lane >> 4;
  const int r16  = lane & 15;
  const int t0   = win << 7;

  short8 wreg[3][16];
#pragma unroll
  for (int tt = 0; tt < 3; ++tt)
#pragma unroll
    for (int kk = 0; kk < 16; ++kk)
      wreg[tt][kk] = *(const short8*)(Whh + (size_t)(w * 64 + tt * 16 + r16) * 512 + kk * 32 + q * 8);

#pragma unroll
  for (int kk = 0; kk < 16; ++kk) {
    short8 v = *(const short8*)(Whh + (size_t)(w * 64 + 48 + r16) * 512 + kk * 32 + q * 8);
    *(short8*)(LDS + w * 16384 + kk * 1024 + q * 256 + r16 * 16) = v;
  }

  // h init into buf0: zero (win 0) or restore saved image
  if (win == 0) {
    short8 z = {0, 0, 0, 0, 0, 0, 0, 0};
    *(short8*)(LDS + 131072 + tid * 32)      = z;
    *(short8*)(LDS + 131072 + tid * 32 + 16) = z;
  } else {
    short8 a = *(const short8*)(hstate + (size_t)g * 8192 + tid * 16);
    short8 b = *(const short8*)(hstate + (size_t)g * 8192 + tid * 16 + 8);
    *(short8*)(LDS + 131072 + tid * 32)      = a;
    *(short8*)(LDS + 131072 + tid * 32 + 16) = b;
  }

  uint32_t rd  = 131072 + q * 256 + r16 * 16;
  uint32_t wrb = 147456 + w * 2048 + (q >> 1) * 256 + r16 * 16 + (q & 1) * 8;
  const uint32_t wlb = w * 16384 + q * 256 + r16 * 16;
  const int jb = w * 64 + q * 4;
  const char* Ub = (const char*)U;
  const uint32_t ubase = (uint32_t)(g * 512 + tid) * 32;
  char* Hc = (char*)Hout;
  uint32_t hoff = (uint32_t)(g * 16 + r16) * 524288u + (uint32_t)jb * 2u + (uint32_t)t0 * 1024u;

  short8 u  = *(const short8*)(Ub + ubase + (uint32_t)t0 * 131072u);
  short8 u2 = *(const short8*)(Ub + ubase + (uint32_t)t0 * 131072u + 16);
  __syncthreads();

  for (int t = t0; t < t0 + 128; ++t) {
    f32x4 D0, D1, D2, D3;
#pragma unroll
    for (int rg = 0; rg < 4; ++rg) {
      D0[rg] = bf16_to_f32((u16)u[rg]);
      D1[rg] = bf16_to_f32((u16)u[rg + 4]);
      D2[rg] = bf16_to_f32((u16)u2[rg]);
      D3[rg] = bf16_to_f32((u16)u2[rg + 4]);
    }
    {
      uint32_t off = ubase + (uint32_t)((t + 1 <= 511) ? (t + 1) : 511) * 131072u;
      u  = *(const short8*)(Ub + off);
      u2 = *(const short8*)(Ub + off + 16);
    }
#pragma unroll
    for (int kk = 0; kk < 16; ++kk) {
      short8 hf = *(const short8*)(LDS + rd + kk * 1024);
      short8 wl = *(const short8*)(LDS + wlb + kk * 1024);
      D0 = mfma16(wreg[0][kk], hf, D0);
      D1 = mfma16(wreg[1][kk], hf, D1);
      D2 = mfma16(wreg[2][kk], hf, D2);
      D3 = mfma16(wl, hf, D3);
    }
#define EPI_TILE(Dt, tt) { \
    float e0 = tanh_e2(Dt[0]), e1 = tanh_e2(Dt[1]); \
    float e2 = tanh_e2(Dt[2]), e3 = tanh_e2(Dt[3]); \
    u32x2 pk; pk[0] = cvt_pk_bf16(e0, e1); pk[1] = cvt_pk_bf16(e2, e3); \
    *(u32x2*)(LDS + wrb + ((tt) >> 1) * 1024 + ((tt) & 1) * 512) = pk; \
    *(u32x2*)(Hc + hoff + (tt) * 32) = pk; \
  }
    EPI_TILE(D0, 0); EPI_TILE(D1, 1); EPI_TILE(D2, 2); EPI_TILE(D3, 3);
#undef EPI_TILE
    hoff += 1024;

    rd ^= 16384; wrb ^= 16384;
    asm volatile("s_waitcnt lgkmcnt(0)" ::: "memory");
    __builtin_amdgcn_s_barrier();
    asm volatile("" ::: "memory");
  }

  // save h (buf0 after even step count)
  {
    short8 a = *(const short8*)(LDS + 131072 + tid * 32);
    short8 b = *(const short8*)(LDS + 131072 + tid * 32 + 16);
    *(short8*)(hstate + (size_t)g * 8192 + tid * 16)     = a;
    *(short8*)(hstate + (size_t)g * 8192 + tid * 16 + 8) = b;
  }

  // final hidden state after last window
  if (win == 3) {
    int b = g * 16 + r16;
    if (b < 125) {
      uint32_t fwr = 131072 + w * 2048 + (q >> 1) * 256 + r16 * 16 + (q & 1) * 8;
#pragma unroll
      for (int tt = 0; tt < 4; ++tt) {
        u32x2 pk = *(const u32x2*)(LDS + fwr + (tt >> 1) * 1024 + (tt & 1) * 512);
        float4 v;
        v.x = __builtin_bit_cast(float, pk[0] << 16);
        v.y = __builtin_bit_cast(float, pk[0] & 0xFFFF0000u);
        v.z = __builtin_bit_cast(float, pk[1] << 16);
        v.w = __builtin_bit_cast(float, pk[1] & 0xFFFF0000u);
        *(float4*)(hidden + (size_t)b * 512 + jb + tt * 16) = v;
      }
    }
  }
}

// ---------------- one 128x128x512 GEMM tile (r6-verified structure) ----------------
// frag=1: bf16 scatter into rec U fragment layout; frag=0: f32 [.][N] + bias.
DEVINL void gemm_tile(char* LDS, const u16* __restrict__ A, const u16* __restrict__ B,
                      const float* __restrict__ bias, void* __restrict__ out,
                      int brow, int bcol, int N, int frag) {
  u16* lA = (u16*)LDS;
  u16* lB = (u16*)(LDS + 16384);
  const int tid  = threadIdx.x;
  const int lane = tid & 63;
  const int wave = tid >> 6;
  const int wr = wave >> 2;
  const int wc = wave & 3;
  const int q   = lane >> 4;
  const int r16 = lane & 15;

  f32x4 acc[4][2];
#pragma unroll
  for (int i = 0; i < 4; ++i)
#pragma unroll
    for (int j = 0; j < 2; ++j) acc[i][j] = (f32x4){0.f, 0.f, 0.f, 0.f};

  for (int kt = 0; kt < 8; ++kt) {
#pragma unroll
    for (int s = 0; s < 2; ++s) {
      int c   = tid * 2 + s;
      int row = c >> 3;
      int cb  = (c & 7) * 16;
      int dsw = cb ^ ((row & 7) << 4);
      short8 va = *(const short8*)(A + (size_t)(brow + row) * 512 + kt * 64 + (cb >> 1));
      *(short8*)((char*)lA + row * 128 + dsw) = va;
      short8 vb = *(const short8*)(B + (size_t)(bcol + row) * 512 + kt * 64 + (cb >> 1));
      *(short8*)((char*)lB + row * 128 + dsw) = vb;
    }
    __syncthreads();
#pragma unroll
    for (int kk = 0; kk < 2; ++kk) {
      short8 af[4], bfr[2];
#pragma unroll
      for (int mt = 0; mt < 4; ++mt) {
        int row = wr * 64 + mt * 16 + r16;
        int byt = (kk * 64 + q * 16) ^ ((row & 7) << 4);
        af[mt] = *(const short8*)((const char*)lA + row * 128 + byt);
      }
#pragma unroll
      for (int nt = 0; nt < 2; ++nt) {
        int row = wc * 32 + nt * 16 + r16;
        int byt = (kk * 64 + q * 16) ^ ((row & 7) << 4);
        bfr[nt] = *(const short8*)((const char*)lB + row * 128 + byt);
      }
#pragma unroll
      for (int mt = 0; mt < 4; ++mt)
#pragma unroll
        for (int nt = 0; nt < 2; ++nt)
          acc[mt][nt] = mfma16(af[mt], bfr[nt], acc[mt][nt]);
    }
    __syncthreads();
  }

#pragma unroll
  for (int mt = 0; mt < 4; ++mt) {
#pragma unroll
    for (int nt = 0; nt < 2; ++nt) {
      int jc = bcol + wc * 32 + nt * 16 + r16;
      float bv = bias[jc];
      if (!frag) {
#pragma unroll
        for (int rg = 0; rg < 4; ++rg) {
          int mg = brow + wr * 64 + mt * 16 + q * 4 + rg;
          ((float*)out)[(size_t)mg * N + jc] = acc[mt][nt][rg] + bv;
        }
      } else {
        int tidc    = (jc >> 6) * 64 + ((jc >> 2) & 3) * 16;   // + (bb&15)
        int colpart = ((jc >> 4) & 3) * 4 + (jc & 3);
#pragma unroll
        for (int rg = 0; rg < 4; ++rg) {
          int mg = brow + wr * 64 + mt * 16 + q * 4 + rg;
          int bb = mg >> 9;        // batch index (T=512)
          int t2 = mg & 511;       // time index
          size_t idx = (((size_t)t2 * 8 + (bb >> 4)) * 512 + tidc + (bb & 15)) * 16 + colpart;
          ((u16*)out)[idx] = f32_to_bf16(acc[mt][nt][rg] + bv);
        }
      }
    }
  }
}

// ---------------- phase kernel: rec1-window | rec2-window | static GEMM tiles ----
// All cross-phase deps flow through kernel boundaries (stream order) -> no locks.
// job encoding: kind*4 + window; kind 0 = gemm1 (Xb->U1), 1 = gemm2 (H1->U2),
// 2 = FC (H2->out, N=1024, 1000 tiles/window; others 500).
__attribute__((amdgpu_flat_work_group_size(512, 512), amdgpu_waves_per_eu(2, 2)))
__global__ void phase(const u16* __restrict__ Whh1, const u16* __restrict__ Whh2,
                      u16* __restrict__ U1, u16* __restrict__ U2,
                      u16* __restrict__ H1, u16* __restrict__ H2,
                      u16* __restrict__ hs1, u16* __restrict__ hs2,
                      const u16* __restrict__ Xb, const u16* __restrict__ Wih1,
                      const u16* __restrict__ Wih2, const u16* __restrict__ FCW,
                      const float* __restrict__ b1, const float* __restrict__ b2,
                      const float* __restrict__ fcb,
                      float* __restrict__ outp, float* __restrict__ hid,
                      int rec1w, int rec2w, int njobs, int j0, int j1, int j2) {
  __shared__ char LDS[163840];
  const int bx = blockIdx.x;
  if (bx < 8) {
    if (rec1w >= 0) rec_window(LDS, bx, Whh1, U1, H1, hid, hs1, rec1w);
  } else if (bx < 16) {
    if (rec2w >= 0) rec_window(LDS, bx - 8, Whh2, U2, H2, hid + 64000, hs2, rec2w);
  } else if (njobs > 0) {
    const int widx = bx - 16;
    int jobs[3] = {j0, j1, j2};
    int cnt[3], total = 0;
    for (int i = 0; i < njobs; ++i) { cnt[i] = ((jobs[i] >> 2) == 2) ? 1000 : 500; total += cnt[i]; }
    for (int tile = widx; tile < total; tile += 240) {
      int rem = tile, jj = 0;
      while (jj < njobs - 1 && rem >= cnt[jj]) { rem -= cnt[jj]; ++jj; }
      int kind = jobs[jj] >> 2, wn = jobs[jj] & 3;
      if (kind == 0)
        gemm_tile(LDS, Xb, Wih1, b1, U1, (rem >> 2) * 512 + wn * 128, (rem & 3) * 128, 512, 1);
      else if (kind == 1)
        gemm_tile(LDS, H1, Wih2, b2, U2, (rem >> 2) * 512 + wn * 128, (rem & 3) * 128, 512, 1);
      else
        gemm_tile(LDS, H2, FCW, fcb, outp, (rem >> 3) * 512 + wn * 128, (rem & 7) * 128, 1024, 0);
    }
  }
}

#define J(k, w) ((k) * 4 + (w))

extern "C" void kernel_launch(void* const* d_in, const int* in_sizes, int n_in,
                              void* d_out, int out_size, void* d_ws, size_t ws_size,
                              hipStream_t stream) {
  const float* x   = (const float*)d_in[0];
  const float* wih = (const float*)d_in[1];   // [2,512,512]
  const float* whh = (const float*)d_in[2];   // [2,512,512]
  const float* bih = (const float*)d_in[3];   // [2,512]
  const float* bhh = (const float*)d_in[4];   // [2,512]
  const float* fcw = (const float*)d_in[5];   // [1024,512]
  const float* fcb = (const float*)d_in[6];   // [1024]

  char* ws = (char*)d_ws;
  float* outp = (float*)d_out;
  float* hid  = outp + 65536000;              // [2][125][512]
  u16*   U1   = (u16*)d_out;                  // U1 frag in d_out (dead before FC)

  // common weights block
  u16* Wih1 = (u16*)(ws + 0);
  u16* Whh1 = (u16*)(ws + 524288);
  u16* Wih2 = (u16*)(ws + 1048576);
  u16* Whh2 = (u16*)(ws + 1572864);
  u16* FCW  = (u16*)(ws + 2097152);
  float* b1 = (float*)(ws + 3145728);
  float* b2 = b1 + 512;
  u16* hs1  = (u16*)(ws + 3276800);           // 128 KB
  u16* hs2  = (u16*)(ws + 3407872);           // 128 KB

  conv_bf16<<<2048, 256, 0, stream>>>(x, (u16*)(ws + 4194304), 32768000L);  // Xb
  conv_bf16<<<256, 256, 0, stream>>>(wih,          Wih1, 262144L);
  conv_bf16<<<256, 256, 0, stream>>>(wih + 262144, Wih2, 262144L);
  conv_bf16<<<256, 256, 0, stream>>>(whh,          Whh1, 262144L);
  conv_bf16<<<256, 256, 0, stream>>>(whh + 262144, Whh2, 262144L);
  conv_bf16<<<512, 256, 0, stream>>>(fcw, FCW, 524288L);
  prep_bias<<<1, 512, 0, stream>>>(bih, bhh, b1, b2);

  u16* Xb = (u16*)(ws + 4194304);

  if (ws_size >= 205520896ull) {
    // ---- pipelined path: U2 overlays Xb (dead after P1); H1, H2 separate ----
    u16* U2 = (u16*)(ws + 4194304);
    u16* H1 = (u16*)(ws + 71303168);
    u16* H2 = (u16*)(ws + 138412032);
#define PH(r1, r2, nj, a, b, c) \
    phase<<<256, 512, 0, stream>>>(Whh1, Whh2, U1, U2, H1, H2, hs1, hs2, Xb, \
                                   Wih1, Wih2, FCW, b1, b2, fcb, outp, hid, \
                                   r1, r2, nj, a, b, c)
    PH(-1, -1, 1, J(0,0), 0, 0);                      // P0: g1w0
    PH( 0, -1, 3, J(0,1), J(0,2), J(0,3));            // P1: rec1w0 | g1w1-3
    PH( 1, -1, 1, J(1,0), 0, 0);                      // P2: rec1w1 | g2w0
    PH( 2,  0, 1, J(1,1), 0, 0);                      // P3: rec1w2 | g2w1 | rec2w0
    PH( 3,  1, 1, J(1,2), 0, 0);                      // P4: rec1w3 | g2w2 | rec2w1
    PH(-1,  2, 2, J(1,3), J(2,0), 0);                 // P5: g2w3 | rec2w2 | FCw0
    PH(-1,  3, 2, J(2,1), J(2,2), 0);                 // P6: rec2w3 | FCw1-2
    PH(-1, -1, 1, J(2,3), 0, 0);                      // P7: FCw3
#undef PH
  } else {
    // ---- sequential fallback: U2 aliases U1 (d_out), H2 aliases H1 ----
    u16* U2 = U1;
    u16* H1 = (u16*)(ws + 70303744);                  // after Xb (65.5MB @4MB)
    u16* H2 = H1;
#define PH(r1, r2, nj, a, b, c) \
    phase<<<256, 512, 0, stream>>>(Whh1, Whh2, U1, U2, H1, H2, hs1, hs2, Xb, \
                                   Wih1, Wih2, FCW, b1, b2, fcb, outp, hid, \
                                   r1, r2, nj, a, b, c)
    PH(-1, -1, 3, J(0,0), J(0,1), J(0,2));            // gemm1 w0-2
    PH(-1, -1, 1, J(0,3), 0, 0);                      // gemm1 w3
    PH( 0, -1, 0, 0, 0, 0);                           // rec1 w0
    PH( 1, -1, 0, 0, 0, 0);
    PH( 2, -1, 0, 0, 0, 0);
    PH( 3, -1, 0, 0, 0, 0);
    PH(-1, -1, 3, J(1,0), J(1,1), J(1,2));            // gemm2 w0-2 (U1 dead)
    PH(-1, -1, 1, J(1,3), 0, 0);
    PH(-1,  0, 0, 0, 0, 0);                           // rec2 w0..w3
    PH(-1,  1, 0, 0, 0, 0);
    PH(-1,  2, 0, 0, 0, 0);
    PH(-1,  3, 0, 0, 0, 0);
    PH(-1, -1, 2, J(2,0), J(2,1), 0);                 // FC w0-1
    PH(-1, -1, 2, J(2,2), J(2,3), 0);                 // FC w2-3
#undef PH
  }

  (void)in_sizes; (void)n_in; (void)out_size;
}

// Round 12
// 1719.983 us; speedup vs baseline: 1.5840x; 1.1070x over previous
//
#include <hip/hip_runtime.h>
#include <hip/hip_bf16.h>
#include <cstdint>

typedef short short8 __attribute__((ext_vector_type(8)));
typedef float f32x4 __attribute__((ext_vector_type(4)));
typedef uint32_t u32x2 __attribute__((ext_vector_type(2)));
typedef unsigned short u16;

#define DEVINL __device__ __forceinline__

DEVINL u16 f32_to_bf16(float f) {
  uint32_t u = __builtin_bit_cast(uint32_t, f);
  u += 0x7FFFu + ((u >> 16) & 1u);   // RTNE; inputs are finite
  return (u16)(u >> 16);
}
DEVINL float bf16_to_f32(u16 b) {
  return __builtin_bit_cast(float, ((uint32_t)b) << 16);
}
DEVINL f32x4 mfma16(short8 a, short8 b, f32x4 c) {
  return __builtin_amdgcn_mfma_f32_16x16x32_bf16(a, b, c, 0, 0, 0);
}
DEVINL float tanh_e2(float x) {
  float e = __builtin_amdgcn_exp2f(x * 2.88539008177793f);
  return 1.f - __fdividef(2.f, 1.f + e);
}
DEVINL uint32_t cvt_pk_bf16(float lo, float hi) {
  uint32_t r;
  asm("v_cvt_pk_bf16_f32 %0, %1, %2" : "=v"(r) : "v"(lo), "v"(hi));
  return r;
}

// ---------------- fp32 -> bf16 convert (weights only) ----------------
__global__ void conv_bf16(const float* __restrict__ src, u16* __restrict__ dst, long n) {
  long i = ((long)blockIdx.x * blockDim.x + threadIdx.x) * 4;
  long stride = (long)gridDim.x * blockDim.x * 4;
  for (; i < n; i += stride) {
    float4 v = *(const float4*)(src + i);
    uint64_t p = (uint64_t)f32_to_bf16(v.x)
               | ((uint64_t)f32_to_bf16(v.y) << 16)
               | ((uint64_t)f32_to_bf16(v.z) << 32)
               | ((uint64_t)f32_to_bf16(v.w) << 48);
    *(uint64_t*)(dst + i) = p;
  }
}

__global__ void prep_bias(const float* __restrict__ bih, const float* __restrict__ bhh,
                          float* __restrict__ b1, float* __restrict__ b2) {
  int i = threadIdx.x;   // 512 threads
  b1[i] = bih[i]       + bhh[i];
  b2[i] = bih[512 + i] + bhh[512 + i];
}

// ---------------- one 64-step recurrence window (r11-verified body) ----------------
DEVINL void rec_window(char* LDS, int g, const u16* __restrict__ Whh,
                       const u16* __restrict__ U, u16* __restrict__ Hout,
                       float* __restrict__ hidden, u16* __restrict__ hstate, int win) {
  const int tid  = threadIdx.x;
  const int lane = tid & 63;
  const int w    = tid >> 6;
  const int q    = lane >> 4;
  const int r16  = lane & 15;
  const int t0   = win << 6;

  short8 wreg[3][16];
#pragma unroll
  for (int tt = 0; tt < 3; ++tt)
#pragma unroll
    for (int kk = 0; kk < 16; ++kk)
      wreg[tt][kk] = *(const short8*)(Whh + (size_t)(w * 64 + tt * 16 + r16) * 512 + kk * 32 + q * 8);

#pragma unroll
  for (int kk = 0; kk < 16; ++kk) {
    short8 v = *(const short8*)(Whh + (size_t)(w * 64 + 48 + r16) * 512 + kk * 32 + q * 8);
    *(short8*)(LDS + w * 16384 + kk * 1024 + q * 256 + r16 * 16) = v;
  }

  if (win == 0) {
    short8 z = {0, 0, 0, 0, 0, 0, 0, 0};
    *(short8*)(LDS + 131072 + tid * 32)      = z;
    *(short8*)(LDS + 131072 + tid * 32 + 16) = z;
  } else {
    short8 a = *(const short8*)(hstate + (size_t)g * 8192 + tid * 16);
    short8 b = *(const short8*)(hstate + (size_t)g * 8192 + tid * 16 + 8);
    *(short8*)(LDS + 131072 + tid * 32)      = a;
    *(short8*)(LDS + 131072 + tid * 32 + 16) = b;
  }

  uint32_t rd  = 131072 + q * 256 + r16 * 16;
  uint32_t wrb = 147456 + w * 2048 + (q >> 1) * 256 + r16 * 16 + (q & 1) * 8;
  const uint32_t wlb = w * 16384 + q * 256 + r16 * 16;
  const int jb = w * 64 + q * 4;
  const char* Ub = (const char*)U;
  const uint32_t ubase = (uint32_t)(g * 512 + tid) * 32;
  char* Hc = (char*)Hout;
  uint32_t hoff = (uint32_t)(g * 16 + r16) * 524288u + (uint32_t)jb * 2u + (uint32_t)t0 * 1024u;

  short8 u  = *(const short8*)(Ub + ubase + (uint32_t)t0 * 131072u);
  short8 u2 = *(const short8*)(Ub + ubase + (uint32_t)t0 * 131072u + 16);
  __syncthreads();

  for (int t = t0; t < t0 + 64; ++t) {
    f32x4 D0, D1, D2, D3;
#pragma unroll
    for (int rg = 0; rg < 4; ++rg) {
      D0[rg] = bf16_to_f32((u16)u[rg]);
      D1[rg] = bf16_to_f32((u16)u[rg + 4]);
      D2[rg] = bf16_to_f32((u16)u2[rg]);
      D3[rg] = bf16_to_f32((u16)u2[rg + 4]);
    }
    {
      uint32_t off = ubase + (uint32_t)((t + 1 <= 511) ? (t + 1) : 511) * 131072u;
      u  = *(const short8*)(Ub + off);
      u2 = *(const short8*)(Ub + off + 16);
    }
#pragma unroll
    for (int kk = 0; kk < 16; ++kk) {
      short8 hf = *(const short8*)(LDS + rd + kk * 1024);
      short8 wl = *(const short8*)(LDS + wlb + kk * 1024);
      D0 = mfma16(wreg[0][kk], hf, D0);
      D1 = mfma16(wreg[1][kk], hf, D1);
      D2 = mfma16(wreg[2][kk], hf, D2);
      D3 = mfma16(wl, hf, D3);
    }
#define EPI_TILE(Dt, tt) { \
    float e0 = tanh_e2(Dt[0]), e1 = tanh_e2(Dt[1]); \
    float e2 = tanh_e2(Dt[2]), e3 = tanh_e2(Dt[3]); \
    u32x2 pk; pk[0] = cvt_pk_bf16(e0, e1); pk[1] = cvt_pk_bf16(e2, e3); \
    *(u32x2*)(LDS + wrb + ((tt) >> 1) * 1024 + ((tt) & 1) * 512) = pk; \
    *(u32x2*)(Hc + hoff + (tt) * 32) = pk; \
  }
    EPI_TILE(D0, 0); EPI_TILE(D1, 1); EPI_TILE(D2, 2); EPI_TILE(D3, 3);
#undef EPI_TILE
    hoff += 1024;

    rd ^= 16384; wrb ^= 16384;
    asm volatile("s_waitcnt lgkmcnt(0)" ::: "memory");
    __builtin_amdgcn_s_barrier();
    asm volatile("" ::: "memory");
  }

  // save h (buf0 after even step count)
  {
    short8 a = *(const short8*)(LDS + 131072 + tid * 32);
    short8 b = *(const short8*)(LDS + 131072 + tid * 32 + 16);
    *(short8*)(hstate + (size_t)g * 8192 + tid * 16)     = a;
    *(short8*)(hstate + (size_t)g * 8192 + tid * 16 + 8) = b;
  }

  if (win == 7) {
    int b = g * 16 + r16;
    if (b < 125) {
      uint32_t fwr = 131072 + w * 2048 + (q >> 1) * 256 + r16 * 16 + (q & 1) * 8;
#pragma unroll
      for (int tt = 0; tt < 4; ++tt) {
        u32x2 pk = *(const u32x2*)(LDS + fwr + (tt >> 1) * 1024 + (tt & 1) * 512);
        float4 v;
        v.x = __builtin_bit_cast(float, pk[0] << 16);
        v.y = __builtin_bit_cast(float, pk[0] & 0xFFFF0000u);
        v.z = __builtin_bit_cast(float, pk[1] << 16);
        v.w = __builtin_bit_cast(float, pk[1] & 0xFFFF0000u);
        *(float4*)(hidden + (size_t)b * 512 + jb + tt * 16) = v;
      }
    }
  }
}

// ---------------- GEMM tile: MR x 128 x 512 ----------------
// MR = 128 or 64. AF32: A is f32 (convert during staging). FRAG: scatter to
// rec U fragment layout (bf16) vs f32 [.][N] + bias.
template <int MR, int AF32, int FRAG>
DEVINL void gemm_tile(char* LDS, const void* __restrict__ Ap,
                      const u16* __restrict__ B, const float* __restrict__ bias,
                      void* __restrict__ out, int brow, int bcol, int N) {
  u16* lA = (u16*)LDS;
  u16* lB = (u16*)(LDS + 16384);
  const int tid  = threadIdx.x;
  const int lane = tid & 63;
  const int wave = tid >> 6;
  const int wr = wave >> 2;          // 0..1
  const int wc = wave & 3;           // 0..3
  const int q   = lane >> 4;
  const int r16 = lane & 15;
  const int MT = MR / 32;            // m-subtiles per wave half

  f32x4 acc[MT][2];
#pragma unroll
  for (int i = 0; i < MT; ++i)
#pragma unroll
    for (int j = 0; j < 2; ++j) acc[i][j] = (f32x4){0.f, 0.f, 0.f, 0.f};

  for (int kt = 0; kt < 8; ++kt) {
    // ---- stage A ----
    if (AF32) {
      // MR=128: 1024 16B-dst chunks, 2/thread; src 32B f32 -> cvt
#pragma unroll
      for (int s = 0; s < 2; ++s) {
        int c   = tid * 2 + s;
        int row = c >> 3;
        int seg = c & 7;
        const float* src = (const float*)Ap + (size_t)(brow + row) * 512 + kt * 64 + seg * 8;
        float4 a0 = *(const float4*)(src);
        float4 a1 = *(const float4*)(src + 4);
        u32x2 p0, p1;
        p0[0] = cvt_pk_bf16(a0.x, a0.y); p0[1] = cvt_pk_bf16(a0.z, a0.w);
        p1[0] = cvt_pk_bf16(a1.x, a1.y); p1[1] = cvt_pk_bf16(a1.z, a1.w);
        int dsw = (seg * 16) ^ ((row & 7) << 4);
        *(u32x2*)((char*)lA + row * 128 + dsw)     = p0;
        *(u32x2*)((char*)lA + row * 128 + (dsw ^ 8)) = p1;   // seg*16+8 swizzle-invariant bit3
      }
    } else {
      const int CH = MR / 64;        // chunks per thread (128->2, 64->1)
#pragma unroll
      for (int s = 0; s < CH; ++s) {
        int c   = tid * CH + s;
        int row = c >> 3;
        int cb  = (c & 7) * 16;
        int dsw = cb ^ ((row & 7) << 4);
        short8 va = *(const short8*)((const u16*)Ap + (size_t)(brow + row) * 512 + kt * 64 + (cb >> 1));
        *(short8*)((char*)lA + row * 128 + dsw) = va;
      }
    }
    // ---- stage B (128 x 64 bf16) ----
#pragma unroll
    for (int s = 0; s < 2; ++s) {
      int c   = tid * 2 + s;
      int row = c >> 3;
      int cb  = (c & 7) * 16;
      int dsw = cb ^ ((row & 7) << 4);
      short8 vb = *(const short8*)(B + (size_t)(bcol + row) * 512 + kt * 64 + (cb >> 1));
      *(short8*)((char*)lB + row * 128 + dsw) = vb;
    }
    __syncthreads();
#pragma unroll
    for (int kk = 0; kk < 2; ++kk) {
      short8 af[MT], bfr[2];
#pragma unroll
      for (int mt = 0; mt < MT; ++mt) {
        int row = wr * (MR / 2) + mt * 16 + r16;
        int byt = (kk * 64 + q * 16) ^ ((row & 7) << 4);
        af[mt] = *(const short8*)((const char*)lA + row * 128 + byt);
      }
#pragma unroll
      for (int nt = 0; nt < 2; ++nt) {
        int row = wc * 32 + nt * 16 + r16;
        int byt = (kk * 64 + q * 16) ^ ((row & 7) << 4);
        bfr[nt] = *(const short8*)((const char*)lB + row * 128 + byt);
      }
#pragma unroll
      for (int mt = 0; mt < MT; ++mt)
#pragma unroll
        for (int nt = 0; nt < 2; ++nt)
          acc[mt][nt] = mfma16(af[mt], bfr[nt], acc[mt][nt]);
    }
    __syncthreads();
  }

#pragma unroll
  for (int mt = 0; mt < MT; ++mt) {
#pragma unroll
    for (int nt = 0; nt < 2; ++nt) {
      int jc = bcol + wc * 32 + nt * 16 + r16;
      float bv = bias[jc];
      if (!FRAG) {
#pragma unroll
        for (int rg = 0; rg < 4; ++rg) {
          int mg = brow + wr * (MR / 2) + mt * 16 + q * 4 + rg;
          ((float*)out)[(size_t)mg * N + jc] = acc[mt][nt][rg] + bv;
        }
      } else {
        int tidc    = (jc >> 6) * 64 + ((jc >> 2) & 3) * 16;   // + (bb&15)
        int colpart = ((jc >> 4) & 3) * 4 + (jc & 3);
#pragma unroll
        for (int rg = 0; rg < 4; ++rg) {
          int mg = brow + wr * (MR / 2) + mt * 16 + q * 4 + rg;
          int bb = mg >> 9;        // batch index (T=512)
          int t2 = mg & 511;       // time index
          size_t idx = (((size_t)t2 * 8 + (bb >> 4)) * 512 + tidc + (bb & 15)) * 16 + colpart;
          ((u16*)out)[idx] = f32_to_bf16(acc[mt][nt][rg] + bv);
        }
      }
    }
  }
}

// ---------------- phase kernel ----------------
// blocks 0-7: rec1 window | 8-15: rec2 window | 16-255: static GEMM tiles.
// job = kind*16 + idx. kind 0: g1 j (500 tiles, 128-row, A=x f32, ->U1)
//                      kind 1: g2 w (500 tiles, 64-row,  A=H1,    ->U2)
//                      kind 2: FC c (1000 tiles, 128-row, A=H2,   ->outp f32)
__attribute__((amdgpu_flat_work_group_size(512, 512), amdgpu_waves_per_eu(2, 2)))
__global__ void phase(const u16* __restrict__ Whh1, const u16* __restrict__ Whh2,
                      u16* __restrict__ U1, u16* __restrict__ U2,
                      u16* __restrict__ H1, u16* __restrict__ H2,
                      u16* __restrict__ hs1, u16* __restrict__ hs2,
                      const float* __restrict__ Xf, const u16* __restrict__ Wih1,
                      const u16* __restrict__ Wih2, const u16* __restrict__ FCW,
                      const float* __restrict__ b1, const float* __restrict__ b2,
                      const float* __restrict__ fcb,
                      float* __restrict__ outp, float* __restrict__ hid,
                      int rec1w, int rec2w, int njobs, int j0, int j1, int j2, int j3) {
  __shared__ char LDS[163840];
  const int bx = blockIdx.x;
  if (bx < 8) {
    if (rec1w >= 0) rec_window(LDS, bx, Whh1, U1, H1, hid, hs1, rec1w);
  } else if (bx < 16) {
    if (rec2w >= 0) rec_window(LDS, bx - 8, Whh2, U2, H2, hid + 64000, hs2, rec2w);
  } else if (njobs > 0) {
    const int widx = bx - 16;
    int jobs[4] = {j0, j1, j2, j3};
    int cnt[4], total = 0;
    for (int i = 0; i < njobs; ++i) { cnt[i] = ((jobs[i] >> 4) == 2) ? 1000 : 500; total += cnt[i]; }
    for (int tile = widx; tile < total; tile += 240) {
      int rem = tile, jj = 0;
      while (jj < njobs - 1 && rem >= cnt[jj]) { rem -= cnt[jj]; ++jj; }
      int kind = jobs[jj] >> 4, wn = jobs[jj] & 15;
      if (kind == 0)
        gemm_tile<128, 1, 1>(LDS, Xf, Wih1, b1, U1,
                             (rem >> 2) * 512 + wn * 128, (rem & 3) * 128, 512);
      else if (kind == 1)
        gemm_tile<64, 0, 1>(LDS, H1, Wih2, b2, U2,
                            (rem >> 2) * 512 + wn * 64, (rem & 3) * 128, 512);
      else
        gemm_tile<128, 0, 0>(LDS, H2, FCW, fcb, outp,
                             (rem >> 3) * 512 + wn * 128, (rem & 7) * 128, 1024);
    }
  }
}

#define J(k, w) ((k) * 16 + (w))

extern "C" void kernel_launch(void* const* d_in, const int* in_sizes, int n_in,
                              void* d_out, int out_size, void* d_ws, size_t ws_size,
                              hipStream_t stream) {
  const float* x   = (const float*)d_in[0];
  const float* wih = (const float*)d_in[1];   // [2,512,512]
  const float* whh = (const float*)d_in[2];   // [2,512,512]
  const float* bih = (const float*)d_in[3];   // [2,512]
  const float* bhh = (const float*)d_in[4];   // [2,512]
  const float* fcw = (const float*)d_in[5];   // [1024,512]
  const float* fcb = (const float*)d_in[6];   // [1024]

  char* ws = (char*)d_ws;
  float* outp = (float*)d_out;
  float* hid  = outp + 65536000;              // [2][125][512]
  u16*   U1   = (u16*)d_out;                  // U1 frag in d_out (dead before FC)

  u16* Wih1 = (u16*)(ws + 0);
  u16* Whh1 = (u16*)(ws + 524288);
  u16* Wih2 = (u16*)(ws + 1048576);
  u16* Whh2 = (u16*)(ws + 1572864);
  u16* FCW  = (u16*)(ws + 2097152);
  float* b1 = (float*)(ws + 3145728);
  float* b2 = b1 + 512;
  u16* hs1  = (u16*)(ws + 3276800);           // 128 KB
  u16* hs2  = (u16*)(ws + 3407872);           // 128 KB

  conv_bf16<<<256, 256, 0, stream>>>(wih,          Wih1, 262144L);
  conv_bf16<<<256, 256, 0, stream>>>(wih + 262144, Wih2, 262144L);
  conv_bf16<<<256, 256, 0, stream>>>(whh,          Whh1, 262144L);
  conv_bf16<<<256, 256, 0, stream>>>(whh + 262144, Whh2, 262144L);
  conv_bf16<<<512, 256, 0, stream>>>(fcw, FCW, 524288L);
  prep_bias<<<1, 512, 0, stream>>>(bih, bhh, b1, b2);

  if (ws_size >= 205520896ull) {
    u16* U2 = (u16*)(ws + 4194304);
    u16* H1 = (u16*)(ws + 71303168);
    u16* H2 = (u16*)(ws + 138412032);
#define PH(r1, r2, nj, a, b, c, d) \
    phase<<<256, 512, 0, stream>>>(Whh1, Whh2, U1, U2, H1, H2, hs1, hs2, x, \
                                   Wih1, Wih2, FCW, b1, b2, fcb, outp, hid, \
                                   r1, r2, nj, a, b, c, d)
    PH(-1, -1, 1, J(0,0), 0, 0, 0);                     // P0:  g1 j0
    PH( 0, -1, 3, J(0,1), J(0,2), J(0,3), 0);           // P1:  rec1w0 | g1 j1-3
    PH( 1, -1, 1, J(1,0), 0, 0, 0);                     // P2:  rec1w1 | g2w0
    PH( 2,  0, 1, J(1,1), 0, 0, 0);                     // P3:  rec1w2 | rec2w0 | g2w1
    PH( 3,  1, 1, J(1,2), 0, 0, 0);                     // P4
    PH( 4,  2, 1, J(1,3), 0, 0, 0);                     // P5
    PH( 5,  3, 1, J(1,4), 0, 0, 0);                     // P6
    PH( 6,  4, 1, J(1,5), 0, 0, 0);                     // P7
    PH( 7,  5, 1, J(1,6), 0, 0, 0);                     // P8:  rec1w7 | rec2w5 | g2w6
    PH(-1,  6, 3, J(1,7), J(2,0), J(2,1), 0);           // P9:  rec2w6 | g2w7 | FC c0,c1
    PH(-1,  7, 1, J(2,2), 0, 0, 0);                     // P10: rec2w7 | FC c2
    PH(-1, -1, 1, J(2,3), 0, 0, 0);                     // P11: FC c3
#undef PH
  } else {
    // sequential fallback (same kernels, strict order; U2/H2 alias U1/H1)
    u16* U2 = U1;
    u16* H1 = (u16*)(ws + 4194304);
    u16* H2 = H1;
#define PH(r1, r2, nj, a, b, c, d) \
    phase<<<256, 512, 0, stream>>>(Whh1, Whh2, U1, U2, H1, H2, hs1, hs2, x, \
                                   Wih1, Wih2, FCW, b1, b2, fcb, outp, hid, \
                                   r1, r2, nj, a, b, c, d)
    PH(-1, -1, 4, J(0,0), J(0,1), J(0,2), J(0,3));      // g1 all
    for (int w = 0; w < 8; ++w) PH(w, -1, 0, 0, 0, 0, 0);
    PH(-1, -1, 4, J(1,0), J(1,1), J(1,2), J(1,3));      // g2 w0-3
    PH(-1, -1, 4, J(1,4), J(1,5), J(1,6), J(1,7));      // g2 w4-7
    for (int w = 0; w < 8; ++w) PH(-1, w, 0, 0, 0, 0, 0);
    PH(-1, -1, 2, J(2,0), J(2,1), 0, 0);                // FC c0-1
    PH(-1, -1, 2, J(2,2), J(2,3), 0, 0);                // FC c2-3
#undef PH
  }

  (void)in_sizes; (void)n_in; (void)out_size;
}

// Round 13
// 1686.546 us; speedup vs baseline: 1.6154x; 1.0198x over previous
//
#include <hip/hip_runtime.h>
#include <hip/hip_bf16.h>
#include <cstdint>

typedef short short8 __attribute__((ext_vector_type(8)));
typedef float f32x4 __attribute__((ext_vector_type(4)));
typedef uint32_t u32x2 __attribute__((ext_vector_type(2)));
typedef unsigned short u16;

#define DEVINL __device__ __forceinline__

DEVINL u16 f32_to_bf16(float f) {
  uint32_t u = __builtin_bit_cast(uint32_t, f);
  u += 0x7FFFu + ((u >> 16) & 1u);   // RTNE; inputs are finite
  return (u16)(u >> 16);
}
DEVINL float bf16_to_f32(u16 b) {
  return __builtin_bit_cast(float, ((uint32_t)b) << 16);
}
DEVINL f32x4 mfma16(short8 a, short8 b, f32x4 c) {
  return __builtin_amdgcn_mfma_f32_16x16x32_bf16(a, b, c, 0, 0, 0);
}
DEVINL float tanh_e2(float x) {
  float e = __builtin_amdgcn_exp2f(x * 2.88539008177793f);
  return 1.f - __fdividef(2.f, 1.f + e);
}
DEVINL uint32_t cvt_pk_bf16(float lo, float hi) {
  uint32_t r;
  asm("v_cvt_pk_bf16_f32 %0, %1, %2" : "=v"(r) : "v"(lo), "v"(hi));
  return r;
}

// ---------------- single-launch weight convert + bias prep ----------------
__global__ void conv_all(const float* __restrict__ wih, const float* __restrict__ whh,
                         const float* __restrict__ fcw, const float* __restrict__ bih,
                         const float* __restrict__ bhh,
                         u16* __restrict__ Wih1, u16* __restrict__ Wih2,
                         u16* __restrict__ Whh1, u16* __restrict__ Whh2,
                         u16* __restrict__ FCW, float* __restrict__ b1,
                         float* __restrict__ b2) {
  const int bx = blockIdx.x, tid = threadIdx.x;
  if (bx == 1536) {
    for (int i = tid; i < 512; i += 256) {
      b1[i] = bih[i]       + bhh[i];
      b2[i] = bih[512 + i] + bhh[512 + i];
    }
    return;
  }
  const float* src; u16* dst; int off;
  if (bx < 256)       { src = wih;          dst = Wih1; off = bx; }
  else if (bx < 512)  { src = wih + 262144; dst = Wih2; off = bx - 256; }
  else if (bx < 768)  { src = whh;          dst = Whh1; off = bx - 512; }
  else if (bx < 1024) { src = whh + 262144; dst = Whh2; off = bx - 768; }
  else                { src = fcw;          dst = FCW;  off = bx - 1024; }
  long i = (long)off * 1024 + tid * 4;
  float4 v = *(const float4*)(src + i);
  uint64_t p = (uint64_t)f32_to_bf16(v.x)
             | ((uint64_t)f32_to_bf16(v.y) << 16)
             | ((uint64_t)f32_to_bf16(v.z) << 32)
             | ((uint64_t)f32_to_bf16(v.w) << 48);
  *(uint64_t*)(dst + i) = p;
}

// ---------------- one 64-step recurrence window (r11-verified body) ----------------
DEVINL void rec_window(char* LDS, int g, const u16* __restrict__ Whh,
                       const u16* __restrict__ U, u16* __restrict__ Hout,
                       float* __restrict__ hidden, u16* __restrict__ hstate, int win) {
  const int tid  = threadIdx.x;
  const int lane = tid & 63;
  const int w    = tid >> 6;
  const int q    = lane >> 4;
  const int r16  = lane & 15;
  const int t0   = win << 6;

  short8 wreg[3][16];
#pragma unroll
  for (int tt = 0; tt < 3; ++tt)
#pragma unroll
    for (int kk = 0; kk < 16; ++kk)
      wreg[tt][kk] = *(const short8*)(Whh + (size_t)(w * 64 + tt * 16 + r16) * 512 + kk * 32 + q * 8);

#pragma unroll
  for (int kk = 0; kk < 16; ++kk) {
    short8 v = *(const short8*)(Whh + (size_t)(w * 64 + 48 + r16) * 512 + kk * 32 + q * 8);
    *(short8*)(LDS + w * 16384 + kk * 1024 + q * 256 + r16 * 16) = v;
  }

  if (win == 0) {
    short8 z = {0, 0, 0, 0, 0, 0, 0, 0};
    *(short8*)(LDS + 131072 + tid * 32)      = z;
    *(short8*)(LDS + 131072 + tid * 32 + 16) = z;
  } else {
    short8 a = *(const short8*)(hstate + (size_t)g * 8192 + tid * 16);
    short8 b = *(const short8*)(hstate + (size_t)g * 8192 + tid * 16 + 8);
    *(short8*)(LDS + 131072 + tid * 32)      = a;
    *(short8*)(LDS + 131072 + tid * 32 + 16) = b;
  }

  uint32_t rd  = 131072 + q * 256 + r16 * 16;
  uint32_t wrb = 147456 + w * 2048 + (q >> 1) * 256 + r16 * 16 + (q & 1) * 8;
  const uint32_t wlb = w * 16384 + q * 256 + r16 * 16;
  const int jb = w * 64 + q * 4;
  const char* Ub = (const char*)U;
  const uint32_t ubase = (uint32_t)(g * 512 + tid) * 32;
  char* Hc = (char*)Hout;
  uint32_t hoff = (uint32_t)(g * 16 + r16) * 524288u + (uint32_t)jb * 2u + (uint32_t)t0 * 1024u;

  short8 u  = *(const short8*)(Ub + ubase + (uint32_t)t0 * 131072u);
  short8 u2 = *(const short8*)(Ub + ubase + (uint32_t)t0 * 131072u + 16);
  __syncthreads();

  for (int t = t0; t < t0 + 64; ++t) {
    f32x4 D0, D1, D2, D3;
#pragma unroll
    for (int rg = 0; rg < 4; ++rg) {
      D0[rg] = bf16_to_f32((u16)u[rg]);
      D1[rg] = bf16_to_f32((u16)u[rg + 4]);
      D2[rg] = bf16_to_f32((u16)u2[rg]);
      D3[rg] = bf16_to_f32((u16)u2[rg + 4]);
    }
    {
      uint32_t off = ubase + (uint32_t)((t + 1 <= 511) ? (t + 1) : 511) * 131072u;
      u  = *(const short8*)(Ub + off);
      u2 = *(const short8*)(Ub + off + 16);
    }
#pragma unroll
    for (int kk = 0; kk < 16; ++kk) {
      short8 hf = *(const short8*)(LDS + rd + kk * 1024);
      short8 wl = *(const short8*)(LDS + wlb + kk * 1024);
      D0 = mfma16(wreg[0][kk], hf, D0);
      D1 = mfma16(wreg[1][kk], hf, D1);
      D2 = mfma16(wreg[2][kk], hf, D2);
      D3 = mfma16(wl, hf, D3);
    }
#define EPI_TILE(Dt, tt) { \
    float e0 = tanh_e2(Dt[0]), e1 = tanh_e2(Dt[1]); \
    float e2 = tanh_e2(Dt[2]), e3 = tanh_e2(Dt[3]); \
    u32x2 pk; pk[0] = cvt_pk_bf16(e0, e1); pk[1] = cvt_pk_bf16(e2, e3); \
    *(u32x2*)(LDS + wrb + ((tt) >> 1) * 1024 + ((tt) & 1) * 512) = pk; \
    *(u32x2*)(Hc + hoff + (tt) * 32) = pk; \
  }
    EPI_TILE(D0, 0); EPI_TILE(D1, 1); EPI_TILE(D2, 2); EPI_TILE(D3, 3);
#undef EPI_TILE
    hoff += 1024;

    rd ^= 16384; wrb ^= 16384;
    asm volatile("s_waitcnt lgkmcnt(0)" ::: "memory");
    __builtin_amdgcn_s_barrier();
    asm volatile("" ::: "memory");
  }

  // save h (buf0 after even step count)
  {
    short8 a = *(const short8*)(LDS + 131072 + tid * 32);
    short8 b = *(const short8*)(LDS + 131072 + tid * 32 + 16);
    *(short8*)(hstate + (size_t)g * 8192 + tid * 16)     = a;
    *(short8*)(hstate + (size_t)g * 8192 + tid * 16 + 8) = b;
  }

  if (win == 7) {
    int b = g * 16 + r16;
    if (b < 125) {
      uint32_t fwr = 131072 + w * 2048 + (q >> 1) * 256 + r16 * 16 + (q & 1) * 8;
#pragma unroll
      for (int tt = 0; tt < 4; ++tt) {
        u32x2 pk = *(const u32x2*)(LDS + fwr + (tt >> 1) * 1024 + (tt & 1) * 512);
        float4 v;
        v.x = __builtin_bit_cast(float, pk[0] << 16);
        v.y = __builtin_bit_cast(float, pk[0] & 0xFFFF0000u);
        v.z = __builtin_bit_cast(float, pk[1] << 16);
        v.w = __builtin_bit_cast(float, pk[1] & 0xFFFF0000u);
        *(float4*)(hidden + (size_t)b * 512 + jb + tt * 16) = v;
      }
    }
  }
}

// ---------------- single 128x128x512 tile, A = f32 (g1 only) ----------------
DEVINL void gemm_g1(char* LDS, const float* __restrict__ Ap, const u16* __restrict__ B,
                    const float* __restrict__ bias, u16* __restrict__ out,
                    int brow, int bcol) {
  u16* lA = (u16*)LDS;
  u16* lB = (u16*)(LDS + 16384);
  const int tid  = threadIdx.x;
  const int lane = tid & 63;
  const int wave = tid >> 6;
  const int wr = wave >> 2;
  const int wc = wave & 3;
  const int q   = lane >> 4;
  const int r16 = lane & 15;

  f32x4 acc[4][2];
#pragma unroll
  for (int i = 0; i < 4; ++i)
#pragma unroll
    for (int j = 0; j < 2; ++j) acc[i][j] = (f32x4){0.f, 0.f, 0.f, 0.f};

  for (int kt = 0; kt < 8; ++kt) {
#pragma unroll
    for (int s = 0; s < 2; ++s) {
      int c   = tid * 2 + s;
      int row = c >> 3;
      int seg = c & 7;
      const float* src = Ap + (size_t)(brow + row) * 512 + kt * 64 + seg * 8;
      float4 a0 = *(const float4*)(src);
      float4 a1 = *(const float4*)(src + 4);
      u32x2 p0, p1;
      p0[0] = cvt_pk_bf16(a0.x, a0.y); p0[1] = cvt_pk_bf16(a0.z, a0.w);
      p1[0] = cvt_pk_bf16(a1.x, a1.y); p1[1] = cvt_pk_bf16(a1.z, a1.w);
      int dsw = (seg * 16) ^ ((row & 7) << 4);
      *(u32x2*)((char*)lA + row * 128 + dsw)       = p0;
      *(u32x2*)((char*)lA + row * 128 + (dsw ^ 8)) = p1;
    }
#pragma unroll
    for (int s = 0; s < 2; ++s) {
      int c   = tid * 2 + s;
      int row = c >> 3;
      int cb  = (c & 7) * 16;
      int dsw = cb ^ ((row & 7) << 4);
      short8 vb = *(const short8*)(B + (size_t)(bcol + row) * 512 + kt * 64 + (cb >> 1));
      *(short8*)((char*)lB + row * 128 + dsw) = vb;
    }
    __syncthreads();
#pragma unroll
    for (int kk = 0; kk < 2; ++kk) {
      short8 af[4], bfr[2];
#pragma unroll
      for (int mt = 0; mt < 4; ++mt) {
        int row = wr * 64 + mt * 16 + r16;
        int byt = (kk * 64 + q * 16) ^ ((row & 7) << 4);
        af[mt] = *(const short8*)((const char*)lA + row * 128 + byt);
      }
#pragma unroll
      for (int nt = 0; nt < 2; ++nt) {
        int row = wc * 32 + nt * 16 + r16;
        int byt = (kk * 64 + q * 16) ^ ((row & 7) << 4);
        bfr[nt] = *(const short8*)((const char*)lB + row * 128 + byt);
      }
#pragma unroll
      for (int mt = 0; mt < 4; ++mt)
#pragma unroll
        for (int nt = 0; nt < 2; ++nt)
          acc[mt][nt] = mfma16(af[mt], bfr[nt], acc[mt][nt]);
    }
    __syncthreads();
  }

#pragma unroll
  for (int mt = 0; mt < 4; ++mt) {
#pragma unroll
    for (int nt = 0; nt < 2; ++nt) {
      int jc = bcol + wc * 32 + nt * 16 + r16;
      float bv = bias[jc];
      int tidc    = (jc >> 6) * 64 + ((jc >> 2) & 3) * 16;
      int colpart = ((jc >> 4) & 3) * 4 + (jc & 3);
#pragma unroll
      for (int rg = 0; rg < 4; ++rg) {
        int mg = brow + wr * 64 + mt * 16 + q * 4 + rg;
        int bb = mg >> 9;
        int t2 = mg & 511;
        size_t idx = (((size_t)t2 * 8 + (bb >> 4)) * 512 + tidc + (bb & 15)) * 16 + colpart;
        out[idx] = f32_to_bf16(acc[mt][nt][rg] + bv);
      }
    }
  }
}

// ---------------- paired 64x128x512 tiles: B staged once for two A tiles ----------
// FRAG=1: bf16 scatter into rec U fragment layout; FRAG=0: f32 [.][N] + bias.
template <int FRAG>
DEVINL void gemm_pair(char* LDS, const u16* __restrict__ Ap, int brow0, int brow1,
                      const u16* __restrict__ B, const float* __restrict__ bias,
                      void* __restrict__ out, int bcol, int N) {
  u16* lB  = (u16*)LDS;                 // 16 KB
  u16* lA0 = (u16*)(LDS + 16384);       // 8 KB
  u16* lA1 = (u16*)(LDS + 24576);       // 8 KB
  const int tid  = threadIdx.x;
  const int lane = tid & 63;
  const int wave = tid >> 6;
  const int wr = wave >> 2;             // 0..1 (rows wr*32..wr*32+32)
  const int wc = wave & 3;              // 0..3
  const int q   = lane >> 4;
  const int r16 = lane & 15;

  f32x4 acc0[2][2], acc1[2][2];
#pragma unroll
  for (int i = 0; i < 2; ++i)
#pragma unroll
    for (int j = 0; j < 2; ++j) {
      acc0[i][j] = (f32x4){0.f, 0.f, 0.f, 0.f};
      acc1[i][j] = (f32x4){0.f, 0.f, 0.f, 0.f};
    }

  for (int kt = 0; kt < 8; ++kt) {
#pragma unroll
    for (int s = 0; s < 2; ++s) {       // B: 128 rows
      int c   = tid * 2 + s;
      int row = c >> 3;
      int cb  = (c & 7) * 16;
      int dsw = cb ^ ((row & 7) << 4);
      short8 vb = *(const short8*)(B + (size_t)(bcol + row) * 512 + kt * 64 + (cb >> 1));
      *(short8*)((char*)lB + row * 128 + dsw) = vb;
    }
    {                                   // A0: 64 rows, 1 chunk/thread
      int row = tid >> 3;
      int cb  = (tid & 7) * 16;
      int dsw = cb ^ ((row & 7) << 4);
      short8 va = *(const short8*)(Ap + (size_t)(brow0 + row) * 512 + kt * 64 + (cb >> 1));
      *(short8*)((char*)lA0 + row * 128 + dsw) = va;
      if (brow1 >= 0) {
        short8 vc = *(const short8*)(Ap + (size_t)(brow1 + row) * 512 + kt * 64 + (cb >> 1));
        *(short8*)((char*)lA1 + row * 128 + dsw) = vc;
      }
    }
    __syncthreads();
#pragma unroll
    for (int kk = 0; kk < 2; ++kk) {
      short8 bfr[2];
#pragma unroll
      for (int nt = 0; nt < 2; ++nt) {
        int row = wc * 32 + nt * 16 + r16;
        int byt = (kk * 64 + q * 16) ^ ((row & 7) << 4);
        bfr[nt] = *(const short8*)((const char*)lB + row * 128 + byt);
      }
#pragma unroll
      for (int mt = 0; mt < 2; ++mt) {
        int row = wr * 32 + mt * 16 + r16;
        int byt = (kk * 64 + q * 16) ^ ((row & 7) << 4);
        short8 a0 = *(const short8*)((const char*)lA0 + row * 128 + byt);
#pragma unroll
        for (int nt = 0; nt < 2; ++nt)
          acc0[mt][nt] = mfma16(a0, bfr[nt], acc0[mt][nt]);
        if (brow1 >= 0) {
          short8 a1 = *(const short8*)((const char*)lA1 + row * 128 + byt);
#pragma unroll
          for (int nt = 0; nt < 2; ++nt)
            acc1[mt][nt] = mfma16(a1, bfr[nt], acc1[mt][nt]);
        }
      }
    }
    __syncthreads();
  }

#define EPI_PAIR(ACC, BROW) { \
  _Pragma("unroll") \
  for (int mt = 0; mt < 2; ++mt) { \
    _Pragma("unroll") \
    for (int nt = 0; nt < 2; ++nt) { \
      int jc = bcol + wc * 32 + nt * 16 + r16; \
      float bv = bias[jc]; \
      if (!FRAG) { \
        _Pragma("unroll") \
        for (int rg = 0; rg < 4; ++rg) { \
          int mg = (BROW) + wr * 32 + mt * 16 + q * 4 + rg; \
          ((float*)out)[(size_t)mg * N + jc] = ACC[mt][nt][rg] + bv; \
        } \
      } else { \
        int tidc    = (jc >> 6) * 64 + ((jc >> 2) & 3) * 16; \
        int colpart = ((jc >> 4) & 3) * 4 + (jc & 3); \
        _Pragma("unroll") \
        for (int rg = 0; rg < 4; ++rg) { \
          int mg = (BROW) + wr * 32 + mt * 16 + q * 4 + rg; \
          int bb = mg >> 9; \
          int t2 = mg & 511; \
          size_t idx = (((size_t)t2 * 8 + (bb >> 4)) * 512 + tidc + (bb & 15)) * 16 + colpart; \
          ((u16*)out)[idx] = f32_to_bf16(ACC[mt][nt][rg] + bv); \
        } \
      } \
    } \
  } }
  EPI_PAIR(acc0, brow0);
  if (brow1 >= 0) EPI_PAIR(acc1, brow1);
#undef EPI_PAIR
}

// ---------------- phase kernel ----------------
// blocks 0-7: rec1 window | 8-15: rec2 window | 16-255: static GEMM jobs.
// job = kind*16 + idx.
//   kind 0: g1 quarter idx (500 single 128-row tiles, A=x f32 -> U1)
//   kind 1: g2 window idx  (252 paired 64-row tiles, A=H1 -> U2)
//   kind 2: FC t-chunk idx (504 paired 64-row tiles, A=H2 -> outp f32)
__attribute__((amdgpu_flat_work_group_size(512, 512), amdgpu_waves_per_eu(2, 2)))
__global__ void phase(const u16* __restrict__ Whh1, const u16* __restrict__ Whh2,
                      u16* __restrict__ U1, u16* __restrict__ U2,
                      u16* __restrict__ H1, u16* __restrict__ H2,
                      u16* __restrict__ hs1, u16* __restrict__ hs2,
                      const float* __restrict__ Xf, const u16* __restrict__ Wih1,
                      const u16* __restrict__ Wih2, const u16* __restrict__ FCW,
                      const float* __restrict__ b1, const float* __restrict__ b2,
                      const float* __restrict__ fcb,
                      float* __restrict__ outp, float* __restrict__ hid,
                      int rec1w, int rec2w, int njobs,
                      int j0, int j1, int j2, int j3, int j4) {
  __shared__ char LDS[163840];
  const int bx = blockIdx.x;
  if (bx < 8) {
    if (rec1w >= 0) rec_window(LDS, bx, Whh1, U1, H1, hid, hs1, rec1w);
  } else if (bx < 16) {
    if (rec2w >= 0) rec_window(LDS, bx - 8, Whh2, U2, H2, hid + 64000, hs2, rec2w);
  } else if (njobs > 0) {
    const int widx = bx - 16;
    int jobs[5] = {j0, j1, j2, j3, j4};
    int cnt[5], total = 0;
    for (int i = 0; i < njobs; ++i) {
      int k = jobs[i] >> 4;
      cnt[i] = (k == 0) ? 500 : (k == 1) ? 252 : 504;
      total += cnt[i];
    }
    for (int tile = widx; tile < total; tile += 240) {
      int rem = tile, jj = 0;
      while (jj < njobs - 1 && rem >= cnt[jj]) { rem -= cnt[jj]; ++jj; }
      int kind = jobs[jj] >> 4, wn = jobs[jj] & 15;
      if (kind == 0) {
        gemm_g1(LDS, Xf, Wih1, b1, U1, (rem >> 2) * 512 + wn * 128, (rem & 3) * 128);
      } else if (kind == 1) {
        int n = rem & 3, p = rem >> 2;
        int m0 = 2 * p, m1 = (p == 62) ? -1 : m0 + 1;
        gemm_pair<1>(LDS, H1, m0 * 512 + wn * 64, (m1 < 0) ? -1 : m1 * 512 + wn * 64,
                     Wih2, b2, U2, n * 128, 512);
      } else {
        int n = rem & 7, p = rem >> 3;
        int m0 = 2 * p, m1 = (p == 62) ? -1 : m0 + 1;
        gemm_pair<0>(LDS, H2, m0 * 512 + wn * 64, (m1 < 0) ? -1 : m1 * 512 + wn * 64,
                     FCW, fcb, outp, n * 128, 1024);
      }
    }
  }
}

#define J(k, w) ((k) * 16 + (w))

extern "C" void kernel_launch(void* const* d_in, const int* in_sizes, int n_in,
                              void* d_out, int out_size, void* d_ws, size_t ws_size,
                              hipStream_t stream) {
  const float* x   = (const float*)d_in[0];
  const float* wih = (const float*)d_in[1];   // [2,512,512]
  const float* whh = (const float*)d_in[2];   // [2,512,512]
  const float* bih = (const float*)d_in[3];   // [2,512]
  const float* bhh = (const float*)d_in[4];   // [2,512]
  const float* fcw = (const float*)d_in[5];   // [1024,512]
  const float* fcb = (const float*)d_in[6];   // [1024]

  char* ws = (char*)d_ws;
  float* outp = (float*)d_out;
  float* hid  = outp + 65536000;              // [2][125][512]
  u16*   U1   = (u16*)d_out;                  // U1 frag in d_out (dead before FC)

  u16* Wih1 = (u16*)(ws + 0);
  u16* Whh1 = (u16*)(ws + 524288);
  u16* Wih2 = (u16*)(ws + 1048576);
  u16* Whh2 = (u16*)(ws + 1572864);
  u16* FCW  = (u16*)(ws + 2097152);
  float* b1 = (float*)(ws + 3145728);
  float* b2 = b1 + 512;
  u16* hs1  = (u16*)(ws + 3276800);           // 128 KB
  u16* hs2  = (u16*)(ws + 3407872);           // 128 KB

  conv_all<<<1537, 256, 0, stream>>>(wih, whh, fcw, bih, bhh,
                                     Wih1, Wih2, Whh1, Whh2, FCW, b1, b2);

  if (ws_size >= 205520896ull) {
    u16* U2 = (u16*)(ws + 4194304);
    u16* H1 = (u16*)(ws + 71303168);
    u16* H2 = (u16*)(ws + 138412032);
#define PH(r1, r2, nj, a, b, c, d, e) \
    phase<<<256, 512, 0, stream>>>(Whh1, Whh2, U1, U2, H1, H2, hs1, hs2, x, \
                                   Wih1, Wih2, FCW, b1, b2, fcb, outp, hid, \
                                   r1, r2, nj, a, b, c, d, e)
    PH(-1, -1, 1, J(0,0), 0, 0, 0, 0);                       // P0:  g1 q0
    PH( 0, -1, 3, J(0,1), J(0,2), J(0,3), 0, 0);             // P1:  rec1w0 | g1 q1-3
    PH( 1, -1, 1, J(1,0), 0, 0, 0, 0);                       // P2:  rec1w1 | g2w0
    PH( 2,  0, 1, J(1,1), 0, 0, 0, 0);                       // P3:  rec1w2 | rec2w0 | g2w1
    PH( 3,  1, 1, J(1,2), 0, 0, 0, 0);                       // P4
    PH( 4,  2, 1, J(1,3), 0, 0, 0, 0);                       // P5
    PH( 5,  3, 1, J(1,4), 0, 0, 0, 0);                       // P6
    PH( 6,  4, 1, J(1,5), 0, 0, 0, 0);                       // P7
    PH( 7,  5, 1, J(1,6), 0, 0, 0, 0);                       // P8:  rec1w7 | rec2w5 | g2w6
    PH(-1,  6, 5, J(1,7), J(2,0), J(2,1), J(2,2), J(2,3));   // P9:  rec2w6 | g2w7 | FC f0-3
    PH(-1,  7, 3, J(2,4), J(2,5), J(2,6), 0, 0);             // P10: rec2w7 | FC f4-6
    PH(-1, -1, 1, J(2,7), 0, 0, 0, 0);                       // P11: FC f7
#undef PH
  } else {
    // sequential fallback (same kernels, strict order; U2/H2 alias U1/H1)
    u16* U2 = U1;
    u16* H1 = (u16*)(ws + 4194304);
    u16* H2 = H1;
#define PH(r1, r2, nj, a, b, c, d, e) \
    phase<<<256, 512, 0, stream>>>(Whh1, Whh2, U1, U2, H1, H2, hs1, hs2, x, \
                                   Wih1, Wih2, FCW, b1, b2, fcb, outp, hid, \
                                   r1, r2, nj, a, b, c, d, e)
    PH(-1, -1, 4, J(0,0), J(0,1), J(0,2), J(0,3), 0);        // g1 all
    for (int w = 0; w < 8; ++w) PH(w, -1, 0, 0, 0, 0, 0, 0); // rec1
    PH(-1, -1, 4, J(1,0), J(1,1), J(1,2), J(1,3), 0);        // g2 w0-3
    PH(-1, -1, 4, J(1,4), J(1,5), J(1,6), J(1,7), 0);        // g2 w4-7
    for (int w = 0; w < 8; ++w) PH(-1, w, 0, 0, 0, 0, 0, 0); // rec2
    PH(-1, -1, 4, J(2,0), J(2,1), J(2,2), J(2,3), 0);        // FC f0-3
    PH(-1, -1, 4, J(2,4), J(2,5), J(2,6), J(2,7), 0);        // FC f4-7
#undef PH
  }

  (void)in_sizes; (void)n_in; (void)out_size;
}